// Round 8
// baseline (422.228 us; speedup 1.0000x reference)
//
#include <hip/hip_runtime.h>
#include <hip/hip_bf16.h>
#include <stdint.h>

// ---------------------------------------------------------------------------
// AFT-Full on MI355X.  exp_wb == 1 exactly (max over singleton axis), so
// num/den are plain sums over t.  GEMMs: 256^2 8-phase single-barrier loop
// (proven R4-bench schedule, GEMM1 bit-identical); GEMM2 runs K=576 dense
// with an odd-NT tail tile (no K padding, no store guards).
// ---------------------------------------------------------------------------

typedef __bf16 vbf16x8 __attribute__((ext_vector_type(8)));
typedef float  vf32x4  __attribute__((ext_vector_type(4)));

#define BB   64
#define TT   576
#define CC   768
#define HID  576
#define NQKV 1792              /* 3*576=1728 padded to 14*128 (qkv row stride) */
#define MR   (BB*TT)           /* 36864 rows */

__device__ __forceinline__ unsigned short f2bf(float f) {
    union { float f; unsigned u; } v; v.f = f;
    unsigned r = v.u + 0x7fffu + ((v.u >> 16) & 1u);   // RNE
    return (unsigned short)(r >> 16);
}
__device__ __forceinline__ float bf2f(unsigned short b) {
    union { unsigned u; float f; } v; v.u = ((unsigned)b) << 16;
    return v.f;
}

// ---- prep: transpose+convert weights to bf16 [N][K], build fused qkv bias --
__global__ void prep_kernel(const float* __restrict__ Wq, const float* __restrict__ Wk,
                            const float* __restrict__ Wv, const float* __restrict__ Wo,
                            const float* __restrict__ bq, const float* __restrict__ bk,
                            const float* __restrict__ bv,
                            unsigned short* __restrict__ WqkvT,   // [1792][768]
                            unsigned short* __restrict__ WoT,     // [768][576] dense
                            float* __restrict__ bqkv)             // [1792]
{
    int idx = blockIdx.x * 256 + threadIdx.x;
    const int NW1 = NQKV * CC;          // 1792*768
    const int NW2 = CC * HID;           // 768*576
    if (idx < NW1) {
        int n = idx / CC, k = idx % CC;
        float v = 0.f;
        if      (n < 576)  v = Wq[k * HID + n];
        else if (n < 1152) v = Wk[k * HID + (n - 576)];
        else if (n < 1728) v = Wv[k * HID + (n - 1152)];
        WqkvT[idx] = f2bf(v);
    } else if (idx < NW1 + NW2) {
        int i = idx - NW1;
        int c = i / HID, h = i % HID;
        WoT[i] = f2bf(Wo[h * CC + c]);
    } else if (idx < NW1 + NW2 + NQKV) {
        int n = idx - NW1 - NW2;
        float v = 0.f;
        if      (n < 576)  v = bq[n];
        else if (n < 1152) v = bk[n - 576];
        else if (n < 1728) v = bv[n - 1152];
        bqkv[n] = v;
    }
}

// ---- convert x (f32) -> bf16, vectorized 4/thread ---------------------------
__global__ void convx_kernel(const float* __restrict__ x, unsigned short* __restrict__ xb, int n4)
{
    int i = blockIdx.x * 256 + threadIdx.x;
    if (i >= n4) return;
    float4 a = ((const float4*)x)[i];
    uint2 o;
    o.x = (unsigned)f2bf(a.x) | ((unsigned)f2bf(a.y) << 16);
    o.y = (unsigned)f2bf(a.z) | ((unsigned)f2bf(a.w) << 16);
    ((uint2*)xb)[i] = o;
}

// ============================================================================
// 256x256 8-phase GEMM, one barrier per phase (R4-bench proven schedule).
// Staging: 1 half-tile per phase,
//   buf1 tile 2t+1: Ah0 @ p8(prev), Ah1 @ p1, Bh0 @ p2, Bh1 @ p3
//   buf0 tile 2t+2: Ah0 @ p4, Ah1 @ p5, Bh0 @ p6, Bh1 @ p7
// Swap gates: vmcnt(2) after MFMA at p4 / p8; VMCNT0 when nothing more staged.
// Odd NT: tile NT-1 (= k2 of the last iteration, staged p4..p7, drained by
// p8's VMCNT0 since s3 is false) is computed in a barrier-free tail block.
// ============================================================================

#define BARR() asm volatile("s_barrier" ::: "memory")
#define MFMA_BEGIN() do { asm volatile("s_waitcnt lgkmcnt(0)" ::: "memory"); \
                          __builtin_amdgcn_sched_barrier(0); \
                          __builtin_amdgcn_s_setprio(1); } while (0)
#define MFMA_END() do { __builtin_amdgcn_s_setprio(0); \
                        __builtin_amdgcn_sched_barrier(0); } while (0)
#define VMCNT2() asm volatile("s_waitcnt vmcnt(2)" ::: "memory")
#define VMCNT0() asm volatile("s_waitcnt vmcnt(0)" ::: "memory")

// stage one 128x64 half-tile (2 x global_load_lds x 512 threads = 16 KB)
#define STG(BI, MAT, H, KT, G) do { \
    const unsigned short* _s0 = (G) + (size_t)(H) * 128 * ldk + (size_t)(KT) * 64 + off0; \
    const unsigned short* _s1 = (G) + (size_t)(H) * 128 * ldk + (size_t)(KT) * 64 + off1; \
    __builtin_amdgcn_global_load_lds((const __attribute__((address_space(1))) void*)_s0, \
        (__attribute__((address_space(3))) void*)&lds[BI][MAT][(H) * 8192 + wave * 512], 16, 0, 0); \
    __builtin_amdgcn_global_load_lds((const __attribute__((address_space(1))) void*)_s1, \
        (__attribute__((address_space(3))) void*)&lds[BI][MAT][(H) * 8192 + 4096 + wave * 512], 16, 0, 0); \
} while (0)

__device__ __forceinline__ void read_a4(const char* L, int base, int fr, int kg, vbf16x8 o[4][2]) {
#pragma unroll
    for (int m = 0; m < 4; ++m)
#pragma unroll
        for (int ks = 0; ks < 2; ++ks) {
            int R = base + m * 16 + fr;
            o[m][ks] = *(const vbf16x8*)(L + (size_t)R * 128 + ((((ks * 4 + kg) ^ (R & 7))) << 4));
        }
}
__device__ __forceinline__ void read_b2(const char* L, int base, int fr, int kg, vbf16x8 o[2][2]) {
#pragma unroll
    for (int n = 0; n < 2; ++n)
#pragma unroll
        for (int ks = 0; ks < 2; ++ks) {
            int R = base + n * 16 + fr;
            o[n][ks] = *(const vbf16x8*)(L + (size_t)R * 128 + ((((ks * 4 + kg) ^ (R & 7))) << 4));
        }
}
__device__ __forceinline__ void mfma16(vf32x4 acc[8][4], const vbf16x8 a[4][2],
                                       const vbf16x8 b[2][2], int mo, int no) {
#pragma unroll
    for (int m = 0; m < 4; ++m)
#pragma unroll
        for (int n = 0; n < 2; ++n)
#pragma unroll
            for (int ks = 0; ks < 2; ++ks)
                acc[mo + m][no + n] = __builtin_amdgcn_mfma_f32_16x16x32_bf16(
                    a[m][ks], b[n][ks], acc[mo + m][no + n], 0, 0, 0);
}

template <int EPI>   // 0: bf16 out, 1: f32 out
__global__ __launch_bounds__(512, 2) void gemm8p(const unsigned short* __restrict__ A,
                                                 const unsigned short* __restrict__ Bt,
                                                 void* __restrict__ Cv,
                                                 const float* __restrict__ bias,
                                                 int N, int ldk, int NT, int nbn)
{
    __shared__ unsigned short lds[2][2][16384];   // [buf][A/B][256*64] = 128 KiB
    int tid = threadIdx.x;
    int lane = tid & 63, wave = tid >> 6;
    int fr = lane & 15, kg = lane >> 4;
    int wm = wave >> 2, wn = wave & 3;

    // XCD-aware swizzle (grid % 8 == 0)
    int cpx = gridDim.x >> 3;
    int wg = (blockIdx.x & 7) * cpx + (blockIdx.x >> 3);
    int bm = wg / nbn, bn = wg % nbn;

    const unsigned short* Ag = A + (size_t)bm * 256 * ldk;
    const unsigned short* Bg = Bt + (size_t)bn * 256 * ldk;

    // per-thread staging offsets (source pre-swizzled: cb ^= row&7)
    int c0 = tid, c1 = 512 + tid;
    int r0 = c0 >> 3, q0 = c0 & 7, r1 = c1 >> 3, q1 = c1 & 7;
    size_t off0 = (size_t)r0 * ldk + (size_t)((q0 ^ (r0 & 7)) << 3);
    size_t off1 = (size_t)r1 * ldk + (size_t)((q1 ^ (r1 & 7)) << 3);

    vf32x4 acc[8][4] = {};
    vbf16x8 a0[4][2], a1[4][2], b0[2][2], b1[2][2];

    // prologue: tile0 -> buf0 (4 halves), tile1 A-h0 -> buf1
    STG(0, 0, 0, 0, Ag); STG(0, 0, 1, 0, Ag);
    STG(0, 1, 0, 0, Bg); STG(0, 1, 1, 0, Bg);
    STG(1, 0, 0, 1, Ag);
    VMCNT2();
    BARR();

    int NH = NT >> 1;
    for (int t = 0; t < NH; ++t) {
        int k1 = 2 * t + 1, k2 = 2 * t + 2, k3 = 2 * t + 3;
        bool s2 = (k2 < NT), s3 = (k3 < NT);
        {   // ---------------- buf0 : tile 2t ----------------
            const char* LA = (const char*)lds[0][0];
            const char* LB = (const char*)lds[0][1];
            // p1
            read_a4(LA, wm * 128, fr, kg, a0);
            read_b2(LB, wn * 64, fr, kg, b0);
            STG(1, 0, 1, k1, Ag);
            MFMA_BEGIN(); mfma16(acc, a0, b0, 0, 0); MFMA_END(); BARR();
            // p2
            read_b2(LB, wn * 64 + 32, fr, kg, b1);
            STG(1, 1, 0, k1, Bg);
            MFMA_BEGIN(); mfma16(acc, a0, b1, 0, 2); MFMA_END(); BARR();
            // p3  (last reads of buf0)
            read_a4(LA, wm * 128 + 64, fr, kg, a1);
            STG(1, 1, 1, k1, Bg);
            MFMA_BEGIN(); mfma16(acc, a1, b1, 4, 2); MFMA_END(); BARR();
            // p4  (stage into buf0 ok: reads done at p3 barrier; gate buf1)
            if (s2) STG(0, 0, 0, k2, Ag);
            MFMA_BEGIN(); mfma16(acc, a1, b0, 4, 0); MFMA_END();
            if (s2) VMCNT2(); else VMCNT0();
            BARR();
        }
        {   // ---------------- buf1 : tile 2t+1 ----------------
            const char* LA = (const char*)lds[1][0];
            const char* LB = (const char*)lds[1][1];
            // p5
            read_a4(LA, wm * 128, fr, kg, a0);
            read_b2(LB, wn * 64, fr, kg, b0);
            if (s2) STG(0, 0, 1, k2, Ag);
            MFMA_BEGIN(); mfma16(acc, a0, b0, 0, 0); MFMA_END(); BARR();
            // p6
            read_b2(LB, wn * 64 + 32, fr, kg, b1);
            if (s2) STG(0, 1, 0, k2, Bg);
            MFMA_BEGIN(); mfma16(acc, a0, b1, 0, 2); MFMA_END(); BARR();
            // p7  (last reads of buf1)
            read_a4(LA, wm * 128 + 64, fr, kg, a1);
            if (s2) STG(0, 1, 1, k2, Bg);
            MFMA_BEGIN(); mfma16(acc, a1, b1, 4, 2); MFMA_END(); BARR();
            // p8  (stage into buf1 ok: reads done at p7 barrier; gate buf0)
            if (s3) STG(1, 0, 0, k3, Ag);
            MFMA_BEGIN(); mfma16(acc, a1, b0, 4, 0); MFMA_END();
            if (s3) VMCNT2(); else VMCNT0();
            BARR();
        }
    }
    if (NT & 1) {
        // tail tile NT-1 in buf0: staged p4..p7 of the final iteration and
        // fully drained by p8's VMCNT0 (s3 false); barrier already passed.
        const char* LA = (const char*)lds[0][0];
        const char* LB = (const char*)lds[0][1];
        read_a4(LA, wm * 128, fr, kg, a0);
        read_b2(LB, wn * 64, fr, kg, b0);
        read_b2(LB, wn * 64 + 32, fr, kg, b1);
        read_a4(LA, wm * 128 + 64, fr, kg, a1);
        MFMA_BEGIN();
        mfma16(acc, a0, b0, 0, 0); mfma16(acc, a0, b1, 0, 2);
        mfma16(acc, a1, b1, 4, 2); mfma16(acc, a1, b0, 4, 0);
        MFMA_END();
    }

    // epilogue: C/D layout col = lane&15, row = (lane>>4)*4 + reg
    int row0 = bm * 256 + wm * 128 + kg * 4;
    int col0 = bn * 256 + wn * 64;
#pragma unroll
    for (int m = 0; m < 8; ++m) {
#pragma unroll
        for (int n = 0; n < 4; ++n) {
            int c = col0 + n * 16 + fr;
            float bb = bias[c];
            int r = row0 + m * 16;
#pragma unroll
            for (int j = 0; j < 4; ++j) {
                float v = acc[m][n][j] + bb;
                if (EPI == 0) ((unsigned short*)Cv)[(size_t)(r + j) * N + c] = f2bf(v);
                else          ((float*)Cv)[(size_t)(r + j) * N + c] = v;
            }
        }
    }
}

// ---- max over batch: maxk[t][h] = max_b k[b,t,h] ----------------------------
__global__ void maxk_kernel(const unsigned short* __restrict__ qkv, float* __restrict__ maxk)
{
    int idx = blockIdx.x * 256 + threadIdx.x;      // t*576 + h
    if (idx >= TT * HID) return;
    int t = idx / HID, h = idx % HID;
    const unsigned short* p = qkv + (size_t)t * NQKV + 576 + h;
    const size_t stride = (size_t)TT * NQKV;
    float m0 = -1e30f, m1 = -1e30f, m2 = -1e30f, m3 = -1e30f;
#pragma unroll 4
    for (int b = 0; b < BB; b += 4) {
        m0 = fmaxf(m0, bf2f(p[(size_t)(b + 0) * stride]));
        m1 = fmaxf(m1, bf2f(p[(size_t)(b + 1) * stride]));
        m2 = fmaxf(m2, bf2f(p[(size_t)(b + 2) * stride]));
        m3 = fmaxf(m3, bf2f(p[(size_t)(b + 3) * stride]));
    }
    maxk[idx] = fmaxf(fmaxf(m0, m1), fmaxf(m2, m3));
}

// ---- num/den partial sums over t (split into 4 chunks, no atomics) ---------
__global__ void numden_kernel(const unsigned short* __restrict__ qkv,
                              const float* __restrict__ maxk,
                              float* __restrict__ num_p, float* __restrict__ den_p)
{
    int b = blockIdx.x, tc = blockIdx.y, h = threadIdx.x;   // 576 threads
    float num = 0.f, den = 0.f;
    int t0 = tc * 144;
    for (int t = t0; t < t0 + 144; ++t) {
        const unsigned short* row = qkv + (size_t)(b * TT + t) * NQKV;
        float kk = bf2f(row[576 + h]);
        float vv = bf2f(row[1152 + h]);
        float e  = __expf(kk - maxk[t * HID + h]);
        den += e;
        num += e * vv;
    }
    int o = (tc * BB + b) * HID + h;
    num_p[o] = num;
    den_p[o] = den;
}

// ---- y = sigmoid(q) * num/den  (bf16, dense row stride 576) ----------------
__global__ void y_kernel(const unsigned short* __restrict__ qkv,
                         const float* __restrict__ num_p, const float* __restrict__ den_p,
                         unsigned short* __restrict__ y)
{
    int idx = blockIdx.x * 256 + threadIdx.x;
    if (idx >= MR * (HID / 8)) return;
    int h8 = idx % (HID / 8), row = idx / (HID / 8);
    int b = row / TT;
    uint4 q4 = *(const uint4*)(qkv + (size_t)row * NQKV + h8 * 8);
    float num[8], den[8];
#pragma unroll
    for (int j = 0; j < 8; ++j) { num[j] = 0.f; den[j] = 0.f; }
#pragma unroll
    for (int tc = 0; tc < 4; ++tc) {
        const float* np = num_p + (size_t)(tc * BB + b) * HID + h8 * 8;
        const float* dp = den_p + (size_t)(tc * BB + b) * HID + h8 * 8;
#pragma unroll
        for (int j = 0; j < 8; ++j) { num[j] += np[j]; den[j] += dp[j]; }
    }
    unsigned qs[4] = { q4.x, q4.y, q4.z, q4.w };
    unsigned o[4];
#pragma unroll
    for (int w2 = 0; w2 < 4; ++w2) {
        float qa = bf2f((unsigned short)(qs[w2] & 0xffff));
        float qb = bf2f((unsigned short)(qs[w2] >> 16));
        float r0 = num[w2 * 2]     / den[w2 * 2];
        float r1 = num[w2 * 2 + 1] / den[w2 * 2 + 1];
        float y0 = (1.f / (1.f + __expf(-qa))) * r0;
        float y1 = (1.f / (1.f + __expf(-qb))) * r1;
        o[w2] = (unsigned)f2bf(y0) | ((unsigned)f2bf(y1) << 16);
    }
    uint4 ov; ov.x = o[0]; ov.y = o[1]; ov.z = o[2]; ov.w = o[3];
    *(uint4*)(y + (size_t)row * HID + h8 * 8) = ov;
}

// ---------------------------------------------------------------------------
extern "C" void kernel_launch(void* const* d_in, const int* in_sizes, int n_in,
                              void* d_out, int out_size, void* d_ws, size_t ws_size,
                              hipStream_t stream)
{
    const float* x  = (const float*)d_in[0];
    const float* Wq = (const float*)d_in[1];
    const float* bq = (const float*)d_in[2];
    const float* Wk = (const float*)d_in[3];
    const float* bk = (const float*)d_in[4];
    const float* Wv = (const float*)d_in[5];
    const float* bv = (const float*)d_in[6];
    const float* Wo = (const float*)d_in[7];
    const float* bo = (const float*)d_in[8];
    float* out = (float*)d_out;

    char* ws = (char*)d_ws;
    size_t off = 0;
    auto alloc = [&](size_t bytes) -> void* {
        off = (off + 255) & ~(size_t)255;
        void* p = ws + off;
        off += bytes;
        return p;
    };

    unsigned short* xb    = (unsigned short*)alloc((size_t)MR * CC * 2);     // 56.6 MB (reused for y[MR][576])
    unsigned short* WqkvT = (unsigned short*)alloc((size_t)NQKV * CC * 2);   // 2.75 MB
    unsigned short* WoT   = (unsigned short*)alloc((size_t)CC * HID * 2);    // 0.88 MB
    float*          bqkv  = (float*)alloc((size_t)NQKV * 4);
    unsigned short* qkv   = (unsigned short*)alloc((size_t)MR * NQKV * 2);   // 132 MB
    float*          maxk  = (float*)alloc((size_t)TT * HID * 4);             // 1.3 MB
    float*          num_p = (float*)alloc((size_t)4 * BB * HID * 4);
    float*          den_p = (float*)alloc((size_t)4 * BB * HID * 4);
    unsigned short* yb    = xb;   // alias: x_bf16 dead after gemm_qkv

    // 1) weights prep
    {
        int total = NQKV * CC + CC * HID + NQKV;
        prep_kernel<<<dim3((total + 255) / 256), dim3(256), 0, stream>>>(
            Wq, Wk, Wv, Wo, bq, bk, bv, WqkvT, WoT, bqkv);
    }
    // 2) x -> bf16
    {
        int n4 = MR * CC / 4;   // 7077888
        convx_kernel<<<dim3(n4 / 256), dim3(256), 0, stream>>>(x, xb, n4);
    }
    // 3) fused QKV GEMM: [36864,768] x [768,1792] -> bf16 qkv   (grid 144*7=1008, NT=12)
    gemm8p<0><<<dim3((MR / 256) * (NQKV / 256)), dim3(512), 0, stream>>>(
        xb, WqkvT, (void*)qkv, bqkv, NQKV, CC, CC / 64, NQKV / 256);
    // 4) max over batch
    maxk_kernel<<<dim3(TT * HID / 256), dim3(256), 0, stream>>>(qkv, maxk);
    // 5) num/den partials
    numden_kernel<<<dim3(BB, 4), dim3(HID), 0, stream>>>(qkv, maxk, num_p, den_p);
    // 6) y = sigmoid(q) * num/den (dense stride 576)
    {
        int total = MR * (HID / 8);   // 2654208
        y_kernel<<<dim3(total / 256), dim3(256), 0, stream>>>(qkv, num_p, den_p, yb);
    }
    // 7) output GEMM: [36864,576] x [576,768] + bo -> f32 out   (grid 144*3=432, NT=9 odd)
    gemm8p<1><<<dim3((MR / 256) * (CC / 256)), dim3(512), 0, stream>>>(
        yb, WoT, (void*)out, bo, CC, HID, HID / 64, CC / 256);
}

// Round 9
// 283.474 us; speedup vs baseline: 1.4895x; 1.4895x over previous
//
#include <hip/hip_runtime.h>
#include <hip/hip_bf16.h>
#include <stdint.h>

// ---------------------------------------------------------------------------
// AFT-Full on MI355X.  exp_wb == 1 exactly (max over singleton axis), so
// num/den are plain sums over t.  GEMMs: 256^2 8-phase single-barrier loop
// (round-4 proven schedule, bit-identical).  numden split 8-way for occupancy.
// NOTE: odd-NT/unpad variants of gemm8p regressed 2x with doubled WRITE_SIZE
// in rounds 5 and 8 -- do not reintroduce runtime-NT/tail machinery.
// ---------------------------------------------------------------------------

typedef __bf16 vbf16x8 __attribute__((ext_vector_type(8)));
typedef float  vf32x4  __attribute__((ext_vector_type(4)));

#define BB   64
#define TT   576
#define CC   768
#define HID  576
#define NQKV 1792              /* 3*576=1728 padded to 14*128 */
#define KPAD 640               /* GEMM2 K: 576 padded to 10*64 */
#define MR   (BB*TT)           /* 36864 rows */
#define NDC  8                 /* numden t-chunks */

__device__ __forceinline__ unsigned short f2bf(float f) {
    union { float f; unsigned u; } v; v.f = f;
    unsigned r = v.u + 0x7fffu + ((v.u >> 16) & 1u);   // RNE
    return (unsigned short)(r >> 16);
}
__device__ __forceinline__ float bf2f(unsigned short b) {
    union { unsigned u; float f; } v; v.u = ((unsigned)b) << 16;
    return v.f;
}

// ---- prep: transpose+convert weights to bf16 [N][K], build fused qkv bias --
__global__ void prep_kernel(const float* __restrict__ Wq, const float* __restrict__ Wk,
                            const float* __restrict__ Wv, const float* __restrict__ Wo,
                            const float* __restrict__ bq, const float* __restrict__ bk,
                            const float* __restrict__ bv,
                            unsigned short* __restrict__ WqkvT,   // [1792][768]
                            unsigned short* __restrict__ WoT,     // [768][640] (K-padded)
                            float* __restrict__ bqkv)             // [1792]
{
    int idx = blockIdx.x * 256 + threadIdx.x;
    const int NW1 = NQKV * CC;          // 1792*768
    const int NW2 = CC * KPAD;          // 768*640
    if (idx < NW1) {
        int n = idx / CC, k = idx % CC;
        float v = 0.f;
        if      (n < 576)  v = Wq[k * HID + n];
        else if (n < 1152) v = Wk[k * HID + (n - 576)];
        else if (n < 1728) v = Wv[k * HID + (n - 1152)];
        WqkvT[idx] = f2bf(v);
    } else if (idx < NW1 + NW2) {
        int i = idx - NW1;
        int c = i / KPAD, h = i % KPAD;
        WoT[i] = (h < HID) ? f2bf(Wo[h * CC + c]) : (unsigned short)0;
    } else if (idx < NW1 + NW2 + NQKV) {
        int n = idx - NW1 - NW2;
        float v = 0.f;
        if      (n < 576)  v = bq[n];
        else if (n < 1152) v = bk[n - 576];
        else if (n < 1728) v = bv[n - 1152];
        bqkv[n] = v;
    }
}

// ---- convert x (f32) -> bf16, vectorized 4/thread ---------------------------
__global__ void convx_kernel(const float* __restrict__ x, unsigned short* __restrict__ xb, int n4)
{
    int i = blockIdx.x * 256 + threadIdx.x;
    if (i >= n4) return;
    float4 a = ((const float4*)x)[i];
    uint2 o;
    o.x = (unsigned)f2bf(a.x) | ((unsigned)f2bf(a.y) << 16);
    o.y = (unsigned)f2bf(a.z) | ((unsigned)f2bf(a.w) << 16);
    ((uint2*)xb)[i] = o;
}

// ============================================================================
// 256x256 8-phase GEMM, one barrier per phase (round-4 proven schedule).
// Staging: 1 half-tile per phase,
//   buf1 tile 2t+1: Ah0 @ p8(prev), Ah1 @ p1, Bh0 @ p2, Bh1 @ p3
//   buf0 tile 2t+2: Ah0 @ p4, Ah1 @ p5, Bh0 @ p6, Bh1 @ p7
// Swap waits: vmcnt(2) after MFMA at p4 (buf1 ready) and p8 (buf0 ready).
// ============================================================================

#define BARR() asm volatile("s_barrier" ::: "memory")
#define MFMA_BEGIN() do { asm volatile("s_waitcnt lgkmcnt(0)" ::: "memory"); \
                          __builtin_amdgcn_sched_barrier(0); \
                          __builtin_amdgcn_s_setprio(1); } while (0)
#define MFMA_END() do { __builtin_amdgcn_s_setprio(0); \
                        __builtin_amdgcn_sched_barrier(0); } while (0)
#define VMCNT2() asm volatile("s_waitcnt vmcnt(2)" ::: "memory")
#define VMCNT0() asm volatile("s_waitcnt vmcnt(0)" ::: "memory")

// stage one 128x64 half-tile (2 x global_load_lds x 512 threads = 16 KB)
#define STG(BI, MAT, H, KT, G) do { \
    const unsigned short* _s0 = (G) + (size_t)(H) * 128 * ldk + (size_t)(KT) * 64 + off0; \
    const unsigned short* _s1 = (G) + (size_t)(H) * 128 * ldk + (size_t)(KT) * 64 + off1; \
    __builtin_amdgcn_global_load_lds((const __attribute__((address_space(1))) void*)_s0, \
        (__attribute__((address_space(3))) void*)&lds[BI][MAT][(H) * 8192 + wave * 512], 16, 0, 0); \
    __builtin_amdgcn_global_load_lds((const __attribute__((address_space(1))) void*)_s1, \
        (__attribute__((address_space(3))) void*)&lds[BI][MAT][(H) * 8192 + 4096 + wave * 512], 16, 0, 0); \
} while (0)

__device__ __forceinline__ void read_a4(const char* L, int base, int fr, int kg, vbf16x8 o[4][2]) {
#pragma unroll
    for (int m = 0; m < 4; ++m)
#pragma unroll
        for (int ks = 0; ks < 2; ++ks) {
            int R = base + m * 16 + fr;
            o[m][ks] = *(const vbf16x8*)(L + (size_t)R * 128 + ((((ks * 4 + kg) ^ (R & 7))) << 4));
        }
}
__device__ __forceinline__ void read_b2(const char* L, int base, int fr, int kg, vbf16x8 o[2][2]) {
#pragma unroll
    for (int n = 0; n < 2; ++n)
#pragma unroll
        for (int ks = 0; ks < 2; ++ks) {
            int R = base + n * 16 + fr;
            o[n][ks] = *(const vbf16x8*)(L + (size_t)R * 128 + ((((ks * 4 + kg) ^ (R & 7))) << 4));
        }
}
__device__ __forceinline__ void mfma16(vf32x4 acc[8][4], const vbf16x8 a[4][2],
                                       const vbf16x8 b[2][2], int mo, int no) {
#pragma unroll
    for (int m = 0; m < 4; ++m)
#pragma unroll
        for (int n = 0; n < 2; ++n)
#pragma unroll
            for (int ks = 0; ks < 2; ++ks)
                acc[mo + m][no + n] = __builtin_amdgcn_mfma_f32_16x16x32_bf16(
                    a[m][ks], b[n][ks], acc[mo + m][no + n], 0, 0, 0);
}

template <int EPI>   // 0: bf16 out, 1: f32 out
__global__ __launch_bounds__(512, 2) void gemm8p(const unsigned short* __restrict__ A,
                                                 const unsigned short* __restrict__ Bt,
                                                 void* __restrict__ Cv,
                                                 const float* __restrict__ bias,
                                                 int N, int ldk, int NITER, int nbn)
{
    __shared__ unsigned short lds[2][2][16384];   // [buf][A/B][256*64] = 128 KiB
    int tid = threadIdx.x;
    int lane = tid & 63, wave = tid >> 6;
    int fr = lane & 15, kg = lane >> 4;
    int wm = wave >> 2, wn = wave & 3;

    // XCD-aware swizzle (grid % 8 == 0)
    int cpx = gridDim.x >> 3;
    int wg = (blockIdx.x & 7) * cpx + (blockIdx.x >> 3);
    int bm = wg / nbn, bn = wg % nbn;

    const unsigned short* Ag = A + (size_t)bm * 256 * ldk;
    const unsigned short* Bg = Bt + (size_t)bn * 256 * ldk;

    // per-thread staging offsets (source pre-swizzled: cb ^= row&7)
    int c0 = tid, c1 = 512 + tid;
    int r0 = c0 >> 3, q0 = c0 & 7, r1 = c1 >> 3, q1 = c1 & 7;
    size_t off0 = (size_t)r0 * ldk + (size_t)((q0 ^ (r0 & 7)) << 3);
    size_t off1 = (size_t)r1 * ldk + (size_t)((q1 ^ (r1 & 7)) << 3);

    vf32x4 acc[8][4] = {};
    vbf16x8 a0[4][2], a1[4][2], b0[2][2], b1[2][2];

    // prologue: tile0 -> buf0 (4 halves), tile1 A-h0 -> buf1
    STG(0, 0, 0, 0, Ag); STG(0, 0, 1, 0, Ag);
    STG(0, 1, 0, 0, Bg); STG(0, 1, 1, 0, Bg);
    STG(1, 0, 0, 1, Ag);
    VMCNT2();
    BARR();

    for (int t = 0; t < NITER; ++t) {
        bool last = (t == NITER - 1);
        int k1 = 2 * t + 1, k2 = 2 * t + 2, k3 = 2 * t + 3;
        {   // ---------------- buf0 : tile 2t ----------------
            const char* LA = (const char*)lds[0][0];
            const char* LB = (const char*)lds[0][1];
            // p1
            read_a4(LA, wm * 128, fr, kg, a0);
            read_b2(LB, wn * 64, fr, kg, b0);
            STG(1, 0, 1, k1, Ag);
            MFMA_BEGIN(); mfma16(acc, a0, b0, 0, 0); MFMA_END(); BARR();
            // p2
            read_b2(LB, wn * 64 + 32, fr, kg, b1);
            STG(1, 1, 0, k1, Bg);
            MFMA_BEGIN(); mfma16(acc, a0, b1, 0, 2); MFMA_END(); BARR();
            // p3  (last reads of buf0)
            read_a4(LA, wm * 128 + 64, fr, kg, a1);
            STG(1, 1, 1, k1, Bg);
            MFMA_BEGIN(); mfma16(acc, a1, b1, 4, 2); MFMA_END(); BARR();
            // p4  (stage into buf0 ok: reads done at p3 barrier; swap-wait for buf1)
            if (!last) STG(0, 0, 0, k2, Ag);
            MFMA_BEGIN(); mfma16(acc, a1, b0, 4, 0); MFMA_END();
            if (!last) VMCNT2(); else VMCNT0();
            BARR();
        }
        {   // ---------------- buf1 : tile 2t+1 ----------------
            const char* LA = (const char*)lds[1][0];
            const char* LB = (const char*)lds[1][1];
            // p5
            read_a4(LA, wm * 128, fr, kg, a0);
            read_b2(LB, wn * 64, fr, kg, b0);
            if (!last) STG(0, 0, 1, k2, Ag);
            MFMA_BEGIN(); mfma16(acc, a0, b0, 0, 0); MFMA_END(); BARR();
            // p6
            read_b2(LB, wn * 64 + 32, fr, kg, b1);
            if (!last) STG(0, 1, 0, k2, Bg);
            MFMA_BEGIN(); mfma16(acc, a0, b1, 0, 2); MFMA_END(); BARR();
            // p7  (last reads of buf1)
            read_a4(LA, wm * 128 + 64, fr, kg, a1);
            if (!last) STG(0, 1, 1, k2, Bg);
            MFMA_BEGIN(); mfma16(acc, a1, b1, 4, 2); MFMA_END(); BARR();
            // p8  (stage into buf1 ok: reads done at p7 barrier; swap-wait for buf0)
            if (!last) STG(1, 0, 0, k3, Ag);
            MFMA_BEGIN(); mfma16(acc, a1, b0, 4, 0); MFMA_END();
            if (!last) VMCNT2(); else VMCNT0();
            BARR();
        }
    }

    // epilogue: C/D layout col = lane&15, row = (lane>>4)*4 + reg
    int row0 = bm * 256 + wm * 128 + kg * 4;
    int col0 = bn * 256 + wn * 64;
#pragma unroll
    for (int m = 0; m < 8; ++m) {
#pragma unroll
        for (int n = 0; n < 4; ++n) {
            int c = col0 + n * 16 + fr;
            float bb = bias[c];
            int r = row0 + m * 16;
#pragma unroll
            for (int j = 0; j < 4; ++j) {
                float v = acc[m][n][j] + bb;
                if (EPI == 0) ((unsigned short*)Cv)[(size_t)(r + j) * N + c] = f2bf(v);
                else          ((float*)Cv)[(size_t)(r + j) * N + c] = v;
            }
        }
    }
}

// ---- max over batch: maxk[t][h] = max_b k[b,t,h] ----------------------------
__global__ void maxk_kernel(const unsigned short* __restrict__ qkv, float* __restrict__ maxk)
{
    int idx = blockIdx.x * 256 + threadIdx.x;      // t*576 + h
    if (idx >= TT * HID) return;
    int t = idx / HID, h = idx % HID;
    const unsigned short* p = qkv + (size_t)t * NQKV + 576 + h;
    const size_t stride = (size_t)TT * NQKV;
    float m0 = -1e30f, m1 = -1e30f, m2 = -1e30f, m3 = -1e30f;
#pragma unroll 4
    for (int b = 0; b < BB; b += 4) {
        m0 = fmaxf(m0, bf2f(p[(size_t)(b + 0) * stride]));
        m1 = fmaxf(m1, bf2f(p[(size_t)(b + 1) * stride]));
        m2 = fmaxf(m2, bf2f(p[(size_t)(b + 2) * stride]));
        m3 = fmaxf(m3, bf2f(p[(size_t)(b + 3) * stride]));
    }
    maxk[idx] = fmaxf(fmaxf(m0, m1), fmaxf(m2, m3));
}

// ---- num/den partial sums over t (split into NDC=8 chunks, no atomics) -----
__global__ void numden_kernel(const unsigned short* __restrict__ qkv,
                              const float* __restrict__ maxk,
                              float* __restrict__ num_p, float* __restrict__ den_p)
{
    int b = blockIdx.x, tc = blockIdx.y, h = threadIdx.x;   // 576 threads
    float num = 0.f, den = 0.f;
    int t0 = tc * (TT / NDC);
    for (int t = t0; t < t0 + TT / NDC; ++t) {
        const unsigned short* row = qkv + (size_t)(b * TT + t) * NQKV;
        float kk = bf2f(row[576 + h]);
        float vv = bf2f(row[1152 + h]);
        float e  = __expf(kk - maxk[t * HID + h]);
        den += e;
        num += e * vv;
    }
    int o = (tc * BB + b) * HID + h;
    num_p[o] = num;
    den_p[o] = den;
}

// ---- y = sigmoid(q) * num/den  (bf16, row stride KPAD=640, zero pad) -------
__global__ void y_kernel(const unsigned short* __restrict__ qkv,
                         const float* __restrict__ num_p, const float* __restrict__ den_p,
                         unsigned short* __restrict__ y)
{
    int idx = blockIdx.x * 256 + threadIdx.x;
    if (idx >= MR * (KPAD / 8)) return;
    int h8 = idx % (KPAD / 8), row = idx / (KPAD / 8);
    if (h8 >= HID / 8) {
        uint4 z = {0, 0, 0, 0};
        *(uint4*)(y + (size_t)row * KPAD + h8 * 8) = z;
        return;
    }
    int b = row / TT;
    uint4 q4 = *(const uint4*)(qkv + (size_t)row * NQKV + h8 * 8);
    float num[8], den[8];
#pragma unroll
    for (int j = 0; j < 8; ++j) { num[j] = 0.f; den[j] = 0.f; }
#pragma unroll
    for (int tc = 0; tc < NDC; ++tc) {
        const float* np = num_p + (size_t)(tc * BB + b) * HID + h8 * 8;
        const float* dp = den_p + (size_t)(tc * BB + b) * HID + h8 * 8;
#pragma unroll
        for (int j = 0; j < 8; ++j) { num[j] += np[j]; den[j] += dp[j]; }
    }
    unsigned qs[4] = { q4.x, q4.y, q4.z, q4.w };
    unsigned o[4];
#pragma unroll
    for (int w2 = 0; w2 < 4; ++w2) {
        float qa = bf2f((unsigned short)(qs[w2] & 0xffff));
        float qb = bf2f((unsigned short)(qs[w2] >> 16));
        float r0 = num[w2 * 2]     / den[w2 * 2];
        float r1 = num[w2 * 2 + 1] / den[w2 * 2 + 1];
        float y0 = (1.f / (1.f + __expf(-qa))) * r0;
        float y1 = (1.f / (1.f + __expf(-qb))) * r1;
        o[w2] = (unsigned)f2bf(y0) | ((unsigned)f2bf(y1) << 16);
    }
    uint4 ov; ov.x = o[0]; ov.y = o[1]; ov.z = o[2]; ov.w = o[3];
    *(uint4*)(y + (size_t)row * KPAD + h8 * 8) = ov;
}

// ---------------------------------------------------------------------------
extern "C" void kernel_launch(void* const* d_in, const int* in_sizes, int n_in,
                              void* d_out, int out_size, void* d_ws, size_t ws_size,
                              hipStream_t stream)
{
    const float* x  = (const float*)d_in[0];
    const float* Wq = (const float*)d_in[1];
    const float* bq = (const float*)d_in[2];
    const float* Wk = (const float*)d_in[3];
    const float* bk = (const float*)d_in[4];
    const float* Wv = (const float*)d_in[5];
    const float* bv = (const float*)d_in[6];
    const float* Wo = (const float*)d_in[7];
    const float* bo = (const float*)d_in[8];
    float* out = (float*)d_out;

    char* ws = (char*)d_ws;
    size_t off = 0;
    auto alloc = [&](size_t bytes) -> void* {
        off = (off + 255) & ~(size_t)255;
        void* p = ws + off;
        off += bytes;
        return p;
    };

    unsigned short* xb    = (unsigned short*)alloc((size_t)MR * CC * 2);     // 56.6 MB (reused for y[MR][640])
    unsigned short* WqkvT = (unsigned short*)alloc((size_t)NQKV * CC * 2);   // 2.75 MB
    unsigned short* WoT   = (unsigned short*)alloc((size_t)CC * KPAD * 2);   // 0.98 MB
    float*          bqkv  = (float*)alloc((size_t)NQKV * 4);
    unsigned short* qkv   = (unsigned short*)alloc((size_t)MR * NQKV * 2);   // 132 MB
    float*          maxk  = (float*)alloc((size_t)TT * HID * 4);             // 1.3 MB
    float*          num_p = (float*)alloc((size_t)NDC * BB * HID * 4);       // 1.18 MB
    float*          den_p = (float*)alloc((size_t)NDC * BB * HID * 4);
    unsigned short* yb    = xb;   // alias: x_bf16 dead after gemm_qkv

    // 1) weights prep
    {
        int total = NQKV * CC + CC * KPAD + NQKV;
        prep_kernel<<<dim3((total + 255) / 256), dim3(256), 0, stream>>>(
            Wq, Wk, Wv, Wo, bq, bk, bv, WqkvT, WoT, bqkv);
    }
    // 2) x -> bf16
    {
        int n4 = MR * CC / 4;   // 7077888
        convx_kernel<<<dim3(n4 / 256), dim3(256), 0, stream>>>(x, xb, n4);
    }
    // 3) fused QKV GEMM: [36864,768] x [768,1792] -> bf16 qkv   (grid 144*7=1008)
    gemm8p<0><<<dim3((MR / 256) * (NQKV / 256)), dim3(512), 0, stream>>>(
        xb, WqkvT, (void*)qkv, bqkv, NQKV, CC, CC / 128, NQKV / 256);
    // 4) max over batch
    maxk_kernel<<<dim3(TT * HID / 256), dim3(256), 0, stream>>>(qkv, maxk);
    // 5) num/den partials (8-way t-split, 512 blocks)
    numden_kernel<<<dim3(BB, NDC), dim3(HID), 0, stream>>>(qkv, maxk, num_p, den_p);
    // 6) y = sigmoid(q) * num/den (row stride 640, zero-padded)
    {
        int total = MR * (KPAD / 8);   // 2949120
        y_kernel<<<dim3(total / 256), dim3(256), 0, stream>>>(qkv, num_p, den_p, yb);
    }
    // 7) output GEMM: [36864,640] x [640,768] + bo -> f32 out   (grid 144*3=432)
    gemm8p<1><<<dim3((MR / 256) * (CC / 256)), dim3(512), 0, stream>>>(
        yb, WoT, (void*)out, bo, CC, KPAD, KPAD / 128, CC / 256);
}

// Round 10
// 261.888 us; speedup vs baseline: 1.6122x; 1.0824x over previous
//
#include <hip/hip_runtime.h>
#include <hip/hip_bf16.h>
#include <stdint.h>

// ---------------------------------------------------------------------------
// AFT-Full on MI355X.  exp_wb == 1 exactly (max over singleton axis), so
// num/den are plain sums over t.  GEMMs: 256^2 8-phase single-barrier loop
// (round-4 proven schedule, bit-identical).  numden NDC=4 (round-4 exact;
// NDC=8 regressed r9).  Do NOT reintroduce odd-NT/tail machinery (r5/r8
// regressed 2x with doubled WRITE_SIZE).
// ---------------------------------------------------------------------------

typedef __bf16 vbf16x8 __attribute__((ext_vector_type(8)));
typedef float  vf32x4  __attribute__((ext_vector_type(4)));

#define BB   64
#define TT   576
#define CC   768
#define HID  576
#define NQKV 1792              /* 3*576=1728 padded to 14*128 */
#define KPAD 640               /* GEMM2 K: 576 padded to 10*64 */
#define MR   (BB*TT)           /* 36864 rows */

__device__ __forceinline__ unsigned short f2bf(float f) {
    union { float f; unsigned u; } v; v.f = f;
    unsigned r = v.u + 0x7fffu + ((v.u >> 16) & 1u);   // RNE
    return (unsigned short)(r >> 16);
}
__device__ __forceinline__ float bf2f(unsigned short b) {
    union { unsigned u; float f; } v; v.u = ((unsigned)b) << 16;
    return v.f;
}

// ---- prep: transpose+convert weights to bf16 [N][K], build fused qkv bias --
__global__ void prep_kernel(const float* __restrict__ Wq, const float* __restrict__ Wk,
                            const float* __restrict__ Wv, const float* __restrict__ Wo,
                            const float* __restrict__ bq, const float* __restrict__ bk,
                            const float* __restrict__ bv,
                            unsigned short* __restrict__ WqkvT,   // [1792][768]
                            unsigned short* __restrict__ WoT,     // [768][640] (K-padded)
                            float* __restrict__ bqkv)             // [1792]
{
    int idx = blockIdx.x * 256 + threadIdx.x;
    const int NW1 = NQKV * CC;          // 1792*768
    const int NW2 = CC * KPAD;          // 768*640
    if (idx < NW1) {
        int n = idx / CC, k = idx % CC;
        float v = 0.f;
        if      (n < 576)  v = Wq[k * HID + n];
        else if (n < 1152) v = Wk[k * HID + (n - 576)];
        else if (n < 1728) v = Wv[k * HID + (n - 1152)];
        WqkvT[idx] = f2bf(v);
    } else if (idx < NW1 + NW2) {
        int i = idx - NW1;
        int c = i / KPAD, h = i % KPAD;
        WoT[i] = (h < HID) ? f2bf(Wo[h * CC + c]) : (unsigned short)0;
    } else if (idx < NW1 + NW2 + NQKV) {
        int n = idx - NW1 - NW2;
        float v = 0.f;
        if      (n < 576)  v = bq[n];
        else if (n < 1152) v = bk[n - 576];
        else if (n < 1728) v = bv[n - 1152];
        bqkv[n] = v;
    }
}

// ---- convert x (f32) -> bf16, vectorized 4/thread ---------------------------
__global__ void convx_kernel(const float* __restrict__ x, unsigned short* __restrict__ xb, int n4)
{
    int i = blockIdx.x * 256 + threadIdx.x;
    if (i >= n4) return;
    float4 a = ((const float4*)x)[i];
    uint2 o;
    o.x = (unsigned)f2bf(a.x) | ((unsigned)f2bf(a.y) << 16);
    o.y = (unsigned)f2bf(a.z) | ((unsigned)f2bf(a.w) << 16);
    ((uint2*)xb)[i] = o;
}

// ============================================================================
// 256x256 8-phase GEMM, one barrier per phase (round-4 proven schedule).
// Staging: 1 half-tile per phase,
//   buf1 tile 2t+1: Ah0 @ p8(prev), Ah1 @ p1, Bh0 @ p2, Bh1 @ p3
//   buf0 tile 2t+2: Ah0 @ p4, Ah1 @ p5, Bh0 @ p6, Bh1 @ p7
// Swap waits: vmcnt(2) after MFMA at p4 (buf1 ready) and p8 (buf0 ready).
// ============================================================================

#define BARR() asm volatile("s_barrier" ::: "memory")
#define MFMA_BEGIN() do { asm volatile("s_waitcnt lgkmcnt(0)" ::: "memory"); \
                          __builtin_amdgcn_sched_barrier(0); \
                          __builtin_amdgcn_s_setprio(1); } while (0)
#define MFMA_END() do { __builtin_amdgcn_s_setprio(0); \
                        __builtin_amdgcn_sched_barrier(0); } while (0)
#define VMCNT2() asm volatile("s_waitcnt vmcnt(2)" ::: "memory")
#define VMCNT0() asm volatile("s_waitcnt vmcnt(0)" ::: "memory")

// stage one 128x64 half-tile (2 x global_load_lds x 512 threads = 16 KB)
#define STG(BI, MAT, H, KT, G) do { \
    const unsigned short* _s0 = (G) + (size_t)(H) * 128 * ldk + (size_t)(KT) * 64 + off0; \
    const unsigned short* _s1 = (G) + (size_t)(H) * 128 * ldk + (size_t)(KT) * 64 + off1; \
    __builtin_amdgcn_global_load_lds((const __attribute__((address_space(1))) void*)_s0, \
        (__attribute__((address_space(3))) void*)&lds[BI][MAT][(H) * 8192 + wave * 512], 16, 0, 0); \
    __builtin_amdgcn_global_load_lds((const __attribute__((address_space(1))) void*)_s1, \
        (__attribute__((address_space(3))) void*)&lds[BI][MAT][(H) * 8192 + 4096 + wave * 512], 16, 0, 0); \
} while (0)

__device__ __forceinline__ void read_a4(const char* L, int base, int fr, int kg, vbf16x8 o[4][2]) {
#pragma unroll
    for (int m = 0; m < 4; ++m)
#pragma unroll
        for (int ks = 0; ks < 2; ++ks) {
            int R = base + m * 16 + fr;
            o[m][ks] = *(const vbf16x8*)(L + (size_t)R * 128 + ((((ks * 4 + kg) ^ (R & 7))) << 4));
        }
}
__device__ __forceinline__ void read_b2(const char* L, int base, int fr, int kg, vbf16x8 o[2][2]) {
#pragma unroll
    for (int n = 0; n < 2; ++n)
#pragma unroll
        for (int ks = 0; ks < 2; ++ks) {
            int R = base + n * 16 + fr;
            o[n][ks] = *(const vbf16x8*)(L + (size_t)R * 128 + ((((ks * 4 + kg) ^ (R & 7))) << 4));
        }
}
__device__ __forceinline__ void mfma16(vf32x4 acc[8][4], const vbf16x8 a[4][2],
                                       const vbf16x8 b[2][2], int mo, int no) {
#pragma unroll
    for (int m = 0; m < 4; ++m)
#pragma unroll
        for (int n = 0; n < 2; ++n)
#pragma unroll
            for (int ks = 0; ks < 2; ++ks)
                acc[mo + m][no + n] = __builtin_amdgcn_mfma_f32_16x16x32_bf16(
                    a[m][ks], b[n][ks], acc[mo + m][no + n], 0, 0, 0);
}

template <int EPI>   // 0: bf16 out, 1: f32 out
__global__ __launch_bounds__(512, 2) void gemm8p(const unsigned short* __restrict__ A,
                                                 const unsigned short* __restrict__ Bt,
                                                 void* __restrict__ Cv,
                                                 const float* __restrict__ bias,
                                                 int N, int ldk, int NITER, int nbn)
{
    __shared__ unsigned short lds[2][2][16384];   // [buf][A/B][256*64] = 128 KiB
    int tid = threadIdx.x;
    int lane = tid & 63, wave = tid >> 6;
    int fr = lane & 15, kg = lane >> 4;
    int wm = wave >> 2, wn = wave & 3;

    // XCD-aware swizzle (grid % 8 == 0)
    int cpx = gridDim.x >> 3;
    int wg = (blockIdx.x & 7) * cpx + (blockIdx.x >> 3);
    int bm = wg / nbn, bn = wg % nbn;

    const unsigned short* Ag = A + (size_t)bm * 256 * ldk;
    const unsigned short* Bg = Bt + (size_t)bn * 256 * ldk;

    // per-thread staging offsets (source pre-swizzled: cb ^= row&7)
    int c0 = tid, c1 = 512 + tid;
    int r0 = c0 >> 3, q0 = c0 & 7, r1 = c1 >> 3, q1 = c1 & 7;
    size_t off0 = (size_t)r0 * ldk + (size_t)((q0 ^ (r0 & 7)) << 3);
    size_t off1 = (size_t)r1 * ldk + (size_t)((q1 ^ (r1 & 7)) << 3);

    vf32x4 acc[8][4] = {};
    vbf16x8 a0[4][2], a1[4][2], b0[2][2], b1[2][2];

    // prologue: tile0 -> buf0 (4 halves), tile1 A-h0 -> buf1
    STG(0, 0, 0, 0, Ag); STG(0, 0, 1, 0, Ag);
    STG(0, 1, 0, 0, Bg); STG(0, 1, 1, 0, Bg);
    STG(1, 0, 0, 1, Ag);
    VMCNT2();
    BARR();

    for (int t = 0; t < NITER; ++t) {
        bool last = (t == NITER - 1);
        int k1 = 2 * t + 1, k2 = 2 * t + 2, k3 = 2 * t + 3;
        {   // ---------------- buf0 : tile 2t ----------------
            const char* LA = (const char*)lds[0][0];
            const char* LB = (const char*)lds[0][1];
            // p1
            read_a4(LA, wm * 128, fr, kg, a0);
            read_b2(LB, wn * 64, fr, kg, b0);
            STG(1, 0, 1, k1, Ag);
            MFMA_BEGIN(); mfma16(acc, a0, b0, 0, 0); MFMA_END(); BARR();
            // p2
            read_b2(LB, wn * 64 + 32, fr, kg, b1);
            STG(1, 1, 0, k1, Bg);
            MFMA_BEGIN(); mfma16(acc, a0, b1, 0, 2); MFMA_END(); BARR();
            // p3  (last reads of buf0)
            read_a4(LA, wm * 128 + 64, fr, kg, a1);
            STG(1, 1, 1, k1, Bg);
            MFMA_BEGIN(); mfma16(acc, a1, b1, 4, 2); MFMA_END(); BARR();
            // p4  (stage into buf0 ok: reads done at p3 barrier; swap-wait for buf1)
            if (!last) STG(0, 0, 0, k2, Ag);
            MFMA_BEGIN(); mfma16(acc, a1, b0, 4, 0); MFMA_END();
            if (!last) VMCNT2(); else VMCNT0();
            BARR();
        }
        {   // ---------------- buf1 : tile 2t+1 ----------------
            const char* LA = (const char*)lds[1][0];
            const char* LB = (const char*)lds[1][1];
            // p5
            read_a4(LA, wm * 128, fr, kg, a0);
            read_b2(LB, wn * 64, fr, kg, b0);
            if (!last) STG(0, 0, 1, k2, Ag);
            MFMA_BEGIN(); mfma16(acc, a0, b0, 0, 0); MFMA_END(); BARR();
            // p6
            read_b2(LB, wn * 64 + 32, fr, kg, b1);
            if (!last) STG(0, 1, 0, k2, Bg);
            MFMA_BEGIN(); mfma16(acc, a0, b1, 0, 2); MFMA_END(); BARR();
            // p7  (last reads of buf1)
            read_a4(LA, wm * 128 + 64, fr, kg, a1);
            if (!last) STG(0, 1, 1, k2, Bg);
            MFMA_BEGIN(); mfma16(acc, a1, b1, 4, 2); MFMA_END(); BARR();
            // p8  (stage into buf1 ok: reads done at p7 barrier; swap-wait for buf0)
            if (!last) STG(1, 0, 0, k3, Ag);
            MFMA_BEGIN(); mfma16(acc, a1, b0, 4, 0); MFMA_END();
            if (!last) VMCNT2(); else VMCNT0();
            BARR();
        }
    }

    // epilogue: C/D layout col = lane&15, row = (lane>>4)*4 + reg
    int row0 = bm * 256 + wm * 128 + kg * 4;
    int col0 = bn * 256 + wn * 64;
#pragma unroll
    for (int m = 0; m < 8; ++m) {
#pragma unroll
        for (int n = 0; n < 4; ++n) {
            int c = col0 + n * 16 + fr;
            float bb = bias[c];
            int r = row0 + m * 16;
#pragma unroll
            for (int j = 0; j < 4; ++j) {
                float v = acc[m][n][j] + bb;
                if (EPI == 0) ((unsigned short*)Cv)[(size_t)(r + j) * N + c] = f2bf(v);
                else          ((float*)Cv)[(size_t)(r + j) * N + c] = v;
            }
        }
    }
}

// ---- max over batch: maxk[t][h] = max_b k[b,t,h] ----------------------------
__global__ void maxk_kernel(const unsigned short* __restrict__ qkv, float* __restrict__ maxk)
{
    int idx = blockIdx.x * 256 + threadIdx.x;      // t*576 + h
    if (idx >= TT * HID) return;
    int t = idx / HID, h = idx % HID;
    const unsigned short* p = qkv + (size_t)t * NQKV + 576 + h;
    const size_t stride = (size_t)TT * NQKV;
    float m0 = -1e30f, m1 = -1e30f, m2 = -1e30f, m3 = -1e30f;
#pragma unroll 4
    for (int b = 0; b < BB; b += 4) {
        m0 = fmaxf(m0, bf2f(p[(size_t)(b + 0) * stride]));
        m1 = fmaxf(m1, bf2f(p[(size_t)(b + 1) * stride]));
        m2 = fmaxf(m2, bf2f(p[(size_t)(b + 2) * stride]));
        m3 = fmaxf(m3, bf2f(p[(size_t)(b + 3) * stride]));
    }
    maxk[idx] = fmaxf(fmaxf(m0, m1), fmaxf(m2, m3));
}

// ---- num/den partial sums over t (split into 4 chunks, no atomics) ---------
__global__ void numden_kernel(const unsigned short* __restrict__ qkv,
                              const float* __restrict__ maxk,
                              float* __restrict__ num_p, float* __restrict__ den_p)
{
    int b = blockIdx.x, tc = blockIdx.y, h = threadIdx.x;   // 576 threads
    float num = 0.f, den = 0.f;
    int t0 = tc * 144;
    for (int t = t0; t < t0 + 144; ++t) {
        const unsigned short* row = qkv + (size_t)(b * TT + t) * NQKV;
        float kk = bf2f(row[576 + h]);
        float vv = bf2f(row[1152 + h]);
        float e  = __expf(kk - maxk[t * HID + h]);
        den += e;
        num += e * vv;
    }
    int o = (tc * BB + b) * HID + h;
    num_p[o] = num;
    den_p[o] = den;
}

// ---- y = sigmoid(q) * num/den  (bf16, row stride KPAD=640, zero pad) -------
__global__ void y_kernel(const unsigned short* __restrict__ qkv,
                         const float* __restrict__ num_p, const float* __restrict__ den_p,
                         unsigned short* __restrict__ y)
{
    int idx = blockIdx.x * 256 + threadIdx.x;
    if (idx >= MR * (KPAD / 8)) return;
    int h8 = idx % (KPAD / 8), row = idx / (KPAD / 8);
    if (h8 >= HID / 8) {
        uint4 z = {0, 0, 0, 0};
        *(uint4*)(y + (size_t)row * KPAD + h8 * 8) = z;
        return;
    }
    int b = row / TT;
    uint4 q4 = *(const uint4*)(qkv + (size_t)row * NQKV + h8 * 8);
    float num[8], den[8];
#pragma unroll
    for (int j = 0; j < 8; ++j) { num[j] = 0.f; den[j] = 0.f; }
#pragma unroll
    for (int tc = 0; tc < 4; ++tc) {
        const float* np = num_p + (size_t)(tc * BB + b) * HID + h8 * 8;
        const float* dp = den_p + (size_t)(tc * BB + b) * HID + h8 * 8;
#pragma unroll
        for (int j = 0; j < 8; ++j) { num[j] += np[j]; den[j] += dp[j]; }
    }
    unsigned qs[4] = { q4.x, q4.y, q4.z, q4.w };
    unsigned o[4];
#pragma unroll
    for (int w2 = 0; w2 < 4; ++w2) {
        float qa = bf2f((unsigned short)(qs[w2] & 0xffff));
        float qb = bf2f((unsigned short)(qs[w2] >> 16));
        float r0 = num[w2 * 2]     / den[w2 * 2];
        float r1 = num[w2 * 2 + 1] / den[w2 * 2 + 1];
        float y0 = (1.f / (1.f + __expf(-qa))) * r0;
        float y1 = (1.f / (1.f + __expf(-qb))) * r1;
        o[w2] = (unsigned)f2bf(y0) | ((unsigned)f2bf(y1) << 16);
    }
    uint4 ov; ov.x = o[0]; ov.y = o[1]; ov.z = o[2]; ov.w = o[3];
    *(uint4*)(y + (size_t)row * KPAD + h8 * 8) = ov;
}

// ---------------------------------------------------------------------------
extern "C" void kernel_launch(void* const* d_in, const int* in_sizes, int n_in,
                              void* d_out, int out_size, void* d_ws, size_t ws_size,
                              hipStream_t stream)
{
    const float* x  = (const float*)d_in[0];
    const float* Wq = (const float*)d_in[1];
    const float* bq = (const float*)d_in[2];
    const float* Wk = (const float*)d_in[3];
    const float* bk = (const float*)d_in[4];
    const float* Wv = (const float*)d_in[5];
    const float* bv = (const float*)d_in[6];
    const float* Wo = (const float*)d_in[7];
    const float* bo = (const float*)d_in[8];
    float* out = (float*)d_out;

    char* ws = (char*)d_ws;
    size_t off = 0;
    auto alloc = [&](size_t bytes) -> void* {
        off = (off + 255) & ~(size_t)255;
        void* p = ws + off;
        off += bytes;
        return p;
    };

    unsigned short* xb    = (unsigned short*)alloc((size_t)MR * CC * 2);     // 56.6 MB (reused for y[MR][640])
    unsigned short* WqkvT = (unsigned short*)alloc((size_t)NQKV * CC * 2);   // 2.75 MB
    unsigned short* WoT   = (unsigned short*)alloc((size_t)CC * KPAD * 2);   // 0.98 MB
    float*          bqkv  = (float*)alloc((size_t)NQKV * 4);
    unsigned short* qkv   = (unsigned short*)alloc((size_t)MR * NQKV * 2);   // 132 MB
    float*          maxk  = (float*)alloc((size_t)TT * HID * 4);             // 1.3 MB
    float*          num_p = (float*)alloc((size_t)4 * BB * HID * 4);
    float*          den_p = (float*)alloc((size_t)4 * BB * HID * 4);
    unsigned short* yb    = xb;   // alias: x_bf16 dead after gemm_qkv

    // 1) weights prep
    {
        int total = NQKV * CC + CC * KPAD + NQKV;
        prep_kernel<<<dim3((total + 255) / 256), dim3(256), 0, stream>>>(
            Wq, Wk, Wv, Wo, bq, bk, bv, WqkvT, WoT, bqkv);
    }
    // 2) x -> bf16
    {
        int n4 = MR * CC / 4;   // 7077888
        convx_kernel<<<dim3(n4 / 256), dim3(256), 0, stream>>>(x, xb, n4);
    }
    // 3) fused QKV GEMM: [36864,768] x [768,1792] -> bf16 qkv   (grid 144*7=1008)
    gemm8p<0><<<dim3((MR / 256) * (NQKV / 256)), dim3(512), 0, stream>>>(
        xb, WqkvT, (void*)qkv, bqkv, NQKV, CC, CC / 128, NQKV / 256);
    // 4) max over batch
    maxk_kernel<<<dim3(TT * HID / 256), dim3(256), 0, stream>>>(qkv, maxk);
    // 5) num/den partials
    numden_kernel<<<dim3(BB, 4), dim3(HID), 0, stream>>>(qkv, maxk, num_p, den_p);
    // 6) y = sigmoid(q) * num/den (row stride 640, zero-padded)
    {
        int total = MR * (KPAD / 8);   // 2949120
        y_kernel<<<dim3(total / 256), dim3(256), 0, stream>>>(qkv, num_p, den_p, yb);
    }
    // 7) output GEMM: [36864,640] x [640,768] + bo -> f32 out   (grid 144*3=432)
    gemm8p<1><<<dim3((MR / 256) * (CC / 256)), dim3(512), 0, stream>>>(
        yb, WoT, (void*)out, bo, CC, KPAD, KPAD / 128, CC / 256);
}

// Round 11
// 257.154 us; speedup vs baseline: 1.6419x; 1.0184x over previous
//
#include <hip/hip_runtime.h>
#include <hip/hip_bf16.h>
#include <stdint.h>

// ---------------------------------------------------------------------------
// AFT-Full on MI355X.  exp_wb == 1 exactly (max over singleton axis), so
// num/den are plain sums over t.  GEMMs: 256^2 8-phase single-barrier loop
// (round-4 proven schedule, bit-identical; 9 variants tried, this is the
// floor -- DO NOT TOUCH).  numden NDC=4.  No odd-NT/tail machinery (r5/r8
// regressed 2x).  This round: prep+convx fused into one dispatch.
// ---------------------------------------------------------------------------

typedef __bf16 vbf16x8 __attribute__((ext_vector_type(8)));
typedef float  vf32x4  __attribute__((ext_vector_type(4)));

#define BB   64
#define TT   576
#define CC   768
#define HID  576
#define NQKV 1792              /* 3*576=1728 padded to 14*128 */
#define KPAD 640               /* GEMM2 K: 576 padded to 10*64 */
#define MR   (BB*TT)           /* 36864 rows */

__device__ __forceinline__ unsigned short f2bf(float f) {
    union { float f; unsigned u; } v; v.f = f;
    unsigned r = v.u + 0x7fffu + ((v.u >> 16) & 1u);   // RNE
    return (unsigned short)(r >> 16);
}
__device__ __forceinline__ float bf2f(unsigned short b) {
    union { unsigned u; float f; } v; v.u = ((unsigned)b) << 16;
    return v.f;
}

// ---- fused prep: x->bf16 convert  +  weight transpose/convert  + qkv bias --
__global__ void prep_kernel(const float* __restrict__ x,
                            const float* __restrict__ Wq, const float* __restrict__ Wk,
                            const float* __restrict__ Wv, const float* __restrict__ Wo,
                            const float* __restrict__ bq, const float* __restrict__ bk,
                            const float* __restrict__ bv,
                            unsigned short* __restrict__ xb,      // [MR*CC] bf16
                            unsigned short* __restrict__ WqkvT,   // [1792][768]
                            unsigned short* __restrict__ WoT,     // [768][640] (K-padded)
                            float* __restrict__ bqkv)             // [1792]
{
    const int N4  = MR * CC / 4;        // 7077888 float4 groups of x
    const int NW1 = NQKV * CC;          // 1792*768
    const int NW2 = CC * KPAD;          // 768*640
    int idx = blockIdx.x * 256 + threadIdx.x;
    if (idx < N4) {
        float4 a = ((const float4*)x)[idx];
        uint2 o;
        o.x = (unsigned)f2bf(a.x) | ((unsigned)f2bf(a.y) << 16);
        o.y = (unsigned)f2bf(a.z) | ((unsigned)f2bf(a.w) << 16);
        ((uint2*)xb)[idx] = o;
        return;
    }
    idx -= N4;
    if (idx < NW1) {
        int n = idx / CC, k = idx % CC;
        float v = 0.f;
        if      (n < 576)  v = Wq[k * HID + n];
        else if (n < 1152) v = Wk[k * HID + (n - 576)];
        else if (n < 1728) v = Wv[k * HID + (n - 1152)];
        WqkvT[idx] = f2bf(v);
    } else if (idx < NW1 + NW2) {
        int i = idx - NW1;
        int c = i / KPAD, h = i % KPAD;
        WoT[i] = (h < HID) ? f2bf(Wo[h * CC + c]) : (unsigned short)0;
    } else if (idx < NW1 + NW2 + NQKV) {
        int n = idx - NW1 - NW2;
        float v = 0.f;
        if      (n < 576)  v = bq[n];
        else if (n < 1152) v = bk[n - 576];
        else if (n < 1728) v = bv[n - 1152];
        bqkv[n] = v;
    }
}

// ============================================================================
// 256x256 8-phase GEMM, one barrier per phase (round-4 proven schedule).
// Staging: 1 half-tile per phase,
//   buf1 tile 2t+1: Ah0 @ p8(prev), Ah1 @ p1, Bh0 @ p2, Bh1 @ p3
//   buf0 tile 2t+2: Ah0 @ p4, Ah1 @ p5, Bh0 @ p6, Bh1 @ p7
// Swap waits: vmcnt(2) after MFMA at p4 (buf1 ready) and p8 (buf0 ready).
// ============================================================================

#define BARR() asm volatile("s_barrier" ::: "memory")
#define MFMA_BEGIN() do { asm volatile("s_waitcnt lgkmcnt(0)" ::: "memory"); \
                          __builtin_amdgcn_sched_barrier(0); \
                          __builtin_amdgcn_s_setprio(1); } while (0)
#define MFMA_END() do { __builtin_amdgcn_s_setprio(0); \
                        __builtin_amdgcn_sched_barrier(0); } while (0)
#define VMCNT2() asm volatile("s_waitcnt vmcnt(2)" ::: "memory")
#define VMCNT0() asm volatile("s_waitcnt vmcnt(0)" ::: "memory")

// stage one 128x64 half-tile (2 x global_load_lds x 512 threads = 16 KB)
#define STG(BI, MAT, H, KT, G) do { \
    const unsigned short* _s0 = (G) + (size_t)(H) * 128 * ldk + (size_t)(KT) * 64 + off0; \
    const unsigned short* _s1 = (G) + (size_t)(H) * 128 * ldk + (size_t)(KT) * 64 + off1; \
    __builtin_amdgcn_global_load_lds((const __attribute__((address_space(1))) void*)_s0, \
        (__attribute__((address_space(3))) void*)&lds[BI][MAT][(H) * 8192 + wave * 512], 16, 0, 0); \
    __builtin_amdgcn_global_load_lds((const __attribute__((address_space(1))) void*)_s1, \
        (__attribute__((address_space(3))) void*)&lds[BI][MAT][(H) * 8192 + 4096 + wave * 512], 16, 0, 0); \
} while (0)

__device__ __forceinline__ void read_a4(const char* L, int base, int fr, int kg, vbf16x8 o[4][2]) {
#pragma unroll
    for (int m = 0; m < 4; ++m)
#pragma unroll
        for (int ks = 0; ks < 2; ++ks) {
            int R = base + m * 16 + fr;
            o[m][ks] = *(const vbf16x8*)(L + (size_t)R * 128 + ((((ks * 4 + kg) ^ (R & 7))) << 4));
        }
}
__device__ __forceinline__ void read_b2(const char* L, int base, int fr, int kg, vbf16x8 o[2][2]) {
#pragma unroll
    for (int n = 0; n < 2; ++n)
#pragma unroll
        for (int ks = 0; ks < 2; ++ks) {
            int R = base + n * 16 + fr;
            o[n][ks] = *(const vbf16x8*)(L + (size_t)R * 128 + ((((ks * 4 + kg) ^ (R & 7))) << 4));
        }
}
__device__ __forceinline__ void mfma16(vf32x4 acc[8][4], const vbf16x8 a[4][2],
                                       const vbf16x8 b[2][2], int mo, int no) {
#pragma unroll
    for (int m = 0; m < 4; ++m)
#pragma unroll
        for (int n = 0; n < 2; ++n)
#pragma unroll
            for (int ks = 0; ks < 2; ++ks)
                acc[mo + m][no + n] = __builtin_amdgcn_mfma_f32_16x16x32_bf16(
                    a[m][ks], b[n][ks], acc[mo + m][no + n], 0, 0, 0);
}

template <int EPI>   // 0: bf16 out, 1: f32 out
__global__ __launch_bounds__(512, 2) void gemm8p(const unsigned short* __restrict__ A,
                                                 const unsigned short* __restrict__ Bt,
                                                 void* __restrict__ Cv,
                                                 const float* __restrict__ bias,
                                                 int N, int ldk, int NITER, int nbn)
{
    __shared__ unsigned short lds[2][2][16384];   // [buf][A/B][256*64] = 128 KiB
    int tid = threadIdx.x;
    int lane = tid & 63, wave = tid >> 6;
    int fr = lane & 15, kg = lane >> 4;
    int wm = wave >> 2, wn = wave & 3;

    // XCD-aware swizzle (grid % 8 == 0)
    int cpx = gridDim.x >> 3;
    int wg = (blockIdx.x & 7) * cpx + (blockIdx.x >> 3);
    int bm = wg / nbn, bn = wg % nbn;

    const unsigned short* Ag = A + (size_t)bm * 256 * ldk;
    const unsigned short* Bg = Bt + (size_t)bn * 256 * ldk;

    // per-thread staging offsets (source pre-swizzled: cb ^= row&7)
    int c0 = tid, c1 = 512 + tid;
    int r0 = c0 >> 3, q0 = c0 & 7, r1 = c1 >> 3, q1 = c1 & 7;
    size_t off0 = (size_t)r0 * ldk + (size_t)((q0 ^ (r0 & 7)) << 3);
    size_t off1 = (size_t)r1 * ldk + (size_t)((q1 ^ (r1 & 7)) << 3);

    vf32x4 acc[8][4] = {};
    vbf16x8 a0[4][2], a1[4][2], b0[2][2], b1[2][2];

    // prologue: tile0 -> buf0 (4 halves), tile1 A-h0 -> buf1
    STG(0, 0, 0, 0, Ag); STG(0, 0, 1, 0, Ag);
    STG(0, 1, 0, 0, Bg); STG(0, 1, 1, 0, Bg);
    STG(1, 0, 0, 1, Ag);
    VMCNT2();
    BARR();

    for (int t = 0; t < NITER; ++t) {
        bool last = (t == NITER - 1);
        int k1 = 2 * t + 1, k2 = 2 * t + 2, k3 = 2 * t + 3;
        {   // ---------------- buf0 : tile 2t ----------------
            const char* LA = (const char*)lds[0][0];
            const char* LB = (const char*)lds[0][1];
            // p1
            read_a4(LA, wm * 128, fr, kg, a0);
            read_b2(LB, wn * 64, fr, kg, b0);
            STG(1, 0, 1, k1, Ag);
            MFMA_BEGIN(); mfma16(acc, a0, b0, 0, 0); MFMA_END(); BARR();
            // p2
            read_b2(LB, wn * 64 + 32, fr, kg, b1);
            STG(1, 1, 0, k1, Bg);
            MFMA_BEGIN(); mfma16(acc, a0, b1, 0, 2); MFMA_END(); BARR();
            // p3  (last reads of buf0)
            read_a4(LA, wm * 128 + 64, fr, kg, a1);
            STG(1, 1, 1, k1, Bg);
            MFMA_BEGIN(); mfma16(acc, a1, b1, 4, 2); MFMA_END(); BARR();
            // p4  (stage into buf0 ok: reads done at p3 barrier; swap-wait for buf1)
            if (!last) STG(0, 0, 0, k2, Ag);
            MFMA_BEGIN(); mfma16(acc, a1, b0, 4, 0); MFMA_END();
            if (!last) VMCNT2(); else VMCNT0();
            BARR();
        }
        {   // ---------------- buf1 : tile 2t+1 ----------------
            const char* LA = (const char*)lds[1][0];
            const char* LB = (const char*)lds[1][1];
            // p5
            read_a4(LA, wm * 128, fr, kg, a0);
            read_b2(LB, wn * 64, fr, kg, b0);
            if (!last) STG(0, 0, 1, k2, Ag);
            MFMA_BEGIN(); mfma16(acc, a0, b0, 0, 0); MFMA_END(); BARR();
            // p6
            read_b2(LB, wn * 64 + 32, fr, kg, b1);
            if (!last) STG(0, 1, 0, k2, Bg);
            MFMA_BEGIN(); mfma16(acc, a0, b1, 0, 2); MFMA_END(); BARR();
            // p7  (last reads of buf1)
            read_a4(LA, wm * 128 + 64, fr, kg, a1);
            if (!last) STG(0, 1, 1, k2, Bg);
            MFMA_BEGIN(); mfma16(acc, a1, b1, 4, 2); MFMA_END(); BARR();
            // p8  (stage into buf1 ok: reads done at p7 barrier; swap-wait for buf0)
            if (!last) STG(1, 0, 0, k3, Ag);
            MFMA_BEGIN(); mfma16(acc, a1, b0, 4, 0); MFMA_END();
            if (!last) VMCNT2(); else VMCNT0();
            BARR();
        }
    }

    // epilogue: C/D layout col = lane&15, row = (lane>>4)*4 + reg
    int row0 = bm * 256 + wm * 128 + kg * 4;
    int col0 = bn * 256 + wn * 64;
#pragma unroll
    for (int m = 0; m < 8; ++m) {
#pragma unroll
        for (int n = 0; n < 4; ++n) {
            int c = col0 + n * 16 + fr;
            float bb = bias[c];
            int r = row0 + m * 16;
#pragma unroll
            for (int j = 0; j < 4; ++j) {
                float v = acc[m][n][j] + bb;
                if (EPI == 0) ((unsigned short*)Cv)[(size_t)(r + j) * N + c] = f2bf(v);
                else          ((float*)Cv)[(size_t)(r + j) * N + c] = v;
            }
        }
    }
}

// ---- max over batch: maxk[t][h] = max_b k[b,t,h] ----------------------------
__global__ void maxk_kernel(const unsigned short* __restrict__ qkv, float* __restrict__ maxk)
{
    int idx = blockIdx.x * 256 + threadIdx.x;      // t*576 + h
    if (idx >= TT * HID) return;
    int t = idx / HID, h = idx % HID;
    const unsigned short* p = qkv + (size_t)t * NQKV + 576 + h;
    const size_t stride = (size_t)TT * NQKV;
    float m0 = -1e30f, m1 = -1e30f, m2 = -1e30f, m3 = -1e30f;
#pragma unroll 4
    for (int b = 0; b < BB; b += 4) {
        m0 = fmaxf(m0, bf2f(p[(size_t)(b + 0) * stride]));
        m1 = fmaxf(m1, bf2f(p[(size_t)(b + 1) * stride]));
        m2 = fmaxf(m2, bf2f(p[(size_t)(b + 2) * stride]));
        m3 = fmaxf(m3, bf2f(p[(size_t)(b + 3) * stride]));
    }
    maxk[idx] = fmaxf(fmaxf(m0, m1), fmaxf(m2, m3));
}

// ---- num/den partial sums over t (split into 4 chunks, no atomics) ---------
__global__ void numden_kernel(const unsigned short* __restrict__ qkv,
                              const float* __restrict__ maxk,
                              float* __restrict__ num_p, float* __restrict__ den_p)
{
    int b = blockIdx.x, tc = blockIdx.y, h = threadIdx.x;   // 576 threads
    float num = 0.f, den = 0.f;
    int t0 = tc * 144;
    for (int t = t0; t < t0 + 144; ++t) {
        const unsigned short* row = qkv + (size_t)(b * TT + t) * NQKV;
        float kk = bf2f(row[576 + h]);
        float vv = bf2f(row[1152 + h]);
        float e  = __expf(kk - maxk[t * HID + h]);
        den += e;
        num += e * vv;
    }
    int o = (tc * BB + b) * HID + h;
    num_p[o] = num;
    den_p[o] = den;
}

// ---- y = sigmoid(q) * num/den  (bf16, row stride KPAD=640, zero pad) -------
__global__ void y_kernel(const unsigned short* __restrict__ qkv,
                         const float* __restrict__ num_p, const float* __restrict__ den_p,
                         unsigned short* __restrict__ y)
{
    int idx = blockIdx.x * 256 + threadIdx.x;
    if (idx >= MR * (KPAD / 8)) return;
    int h8 = idx % (KPAD / 8), row = idx / (KPAD / 8);
    if (h8 >= HID / 8) {
        uint4 z = {0, 0, 0, 0};
        *(uint4*)(y + (size_t)row * KPAD + h8 * 8) = z;
        return;
    }
    int b = row / TT;
    uint4 q4 = *(const uint4*)(qkv + (size_t)row * NQKV + h8 * 8);
    float num[8], den[8];
#pragma unroll
    for (int j = 0; j < 8; ++j) { num[j] = 0.f; den[j] = 0.f; }
#pragma unroll
    for (int tc = 0; tc < 4; ++tc) {
        const float* np = num_p + (size_t)(tc * BB + b) * HID + h8 * 8;
        const float* dp = den_p + (size_t)(tc * BB + b) * HID + h8 * 8;
#pragma unroll
        for (int j = 0; j < 8; ++j) { num[j] += np[j]; den[j] += dp[j]; }
    }
    unsigned qs[4] = { q4.x, q4.y, q4.z, q4.w };
    unsigned o[4];
#pragma unroll
    for (int w2 = 0; w2 < 4; ++w2) {
        float qa = bf2f((unsigned short)(qs[w2] & 0xffff));
        float qb = bf2f((unsigned short)(qs[w2] >> 16));
        float r0 = num[w2 * 2]     / den[w2 * 2];
        float r1 = num[w2 * 2 + 1] / den[w2 * 2 + 1];
        float y0 = (1.f / (1.f + __expf(-qa))) * r0;
        float y1 = (1.f / (1.f + __expf(-qb))) * r1;
        o[w2] = (unsigned)f2bf(y0) | ((unsigned)f2bf(y1) << 16);
    }
    uint4 ov; ov.x = o[0]; ov.y = o[1]; ov.z = o[2]; ov.w = o[3];
    *(uint4*)(y + (size_t)row * KPAD + h8 * 8) = ov;
}

// ---------------------------------------------------------------------------
extern "C" void kernel_launch(void* const* d_in, const int* in_sizes, int n_in,
                              void* d_out, int out_size, void* d_ws, size_t ws_size,
                              hipStream_t stream)
{
    const float* x  = (const float*)d_in[0];
    const float* Wq = (const float*)d_in[1];
    const float* bq = (const float*)d_in[2];
    const float* Wk = (const float*)d_in[3];
    const float* bk = (const float*)d_in[4];
    const float* Wv = (const float*)d_in[5];
    const float* bv = (const float*)d_in[6];
    const float* Wo = (const float*)d_in[7];
    const float* bo = (const float*)d_in[8];
    float* out = (float*)d_out;

    char* ws = (char*)d_ws;
    size_t off = 0;
    auto alloc = [&](size_t bytes) -> void* {
        off = (off + 255) & ~(size_t)255;
        void* p = ws + off;
        off += bytes;
        return p;
    };

    unsigned short* xb    = (unsigned short*)alloc((size_t)MR * CC * 2);     // 56.6 MB (reused for y[MR][640])
    unsigned short* WqkvT = (unsigned short*)alloc((size_t)NQKV * CC * 2);   // 2.75 MB
    unsigned short* WoT   = (unsigned short*)alloc((size_t)CC * KPAD * 2);   // 0.98 MB
    float*          bqkv  = (float*)alloc((size_t)NQKV * 4);
    unsigned short* qkv   = (unsigned short*)alloc((size_t)MR * NQKV * 2);   // 132 MB
    float*          maxk  = (float*)alloc((size_t)TT * HID * 4);             // 1.3 MB
    float*          num_p = (float*)alloc((size_t)4 * BB * HID * 4);
    float*          den_p = (float*)alloc((size_t)4 * BB * HID * 4);
    unsigned short* yb    = xb;   // alias: x_bf16 dead after gemm_qkv

    // 1) fused prep: x->bf16 + weight transpose/convert + bias pack
    {
        int total = MR * CC / 4 + NQKV * CC + CC * KPAD + NQKV;   // 8947456
        prep_kernel<<<dim3((total + 255) / 256), dim3(256), 0, stream>>>(
            x, Wq, Wk, Wv, Wo, bq, bk, bv, xb, WqkvT, WoT, bqkv);
    }
    // 2) fused QKV GEMM: [36864,768] x [768,1792] -> bf16 qkv   (grid 144*7=1008)
    gemm8p<0><<<dim3((MR / 256) * (NQKV / 256)), dim3(512), 0, stream>>>(
        xb, WqkvT, (void*)qkv, bqkv, NQKV, CC, CC / 128, NQKV / 256);
    // 3) max over batch
    maxk_kernel<<<dim3(TT * HID / 256), dim3(256), 0, stream>>>(qkv, maxk);
    // 4) num/den partials
    numden_kernel<<<dim3(BB, 4), dim3(HID), 0, stream>>>(qkv, maxk, num_p, den_p);
    // 5) y = sigmoid(q) * num/den (row stride 640, zero-padded)
    {
        int total = MR * (KPAD / 8);   // 2949120
        y_kernel<<<dim3(total / 256), dim3(256), 0, stream>>>(qkv, num_p, den_p, yb);
    }
    // 6) output GEMM: [36864,640] x [640,768] + bo -> f32 out   (grid 144*3=432)
    gemm8p<1><<<dim3((MR / 256) * (CC / 256)), dim3(512), 0, stream>>>(
        yb, WoT, (void*)out, bo, CC, KPAD, KPAD / 128, CC / 256);
}

// Round 12
// 252.875 us; speedup vs baseline: 1.6697x; 1.0169x over previous
//
#include <hip/hip_runtime.h>
#include <hip/hip_bf16.h>
#include <stdint.h>

// ---------------------------------------------------------------------------
// AFT-Full on MI355X.  exp_wb == 1 exactly (max over singleton axis), so
// num/den are plain sums over t.  GEMMs: 256^2 8-phase single-barrier loop
// (round-4 proven schedule, bit-identical; 9 variants tried, this is the
// floor -- DO NOT TOUCH).  numden NDC=4.  No odd-NT/tail machinery (r5/r8
// regressed 2x).  prep+convx fused (r11, -4.7us).  This round: y pad-write
// removed -- GEMM2's WoT pad rows are exact zeros, so y pad columns
// contribute value*0 = 0 for any finite stale data (xb rewritten each call).
// ---------------------------------------------------------------------------

typedef __bf16 vbf16x8 __attribute__((ext_vector_type(8)));
typedef float  vf32x4  __attribute__((ext_vector_type(4)));

#define BB   64
#define TT   576
#define CC   768
#define HID  576
#define NQKV 1792              /* 3*576=1728 padded to 14*128 */
#define KPAD 640               /* GEMM2 K: 576 padded to 10*64 */
#define MR   (BB*TT)           /* 36864 rows */

__device__ __forceinline__ unsigned short f2bf(float f) {
    union { float f; unsigned u; } v; v.f = f;
    unsigned r = v.u + 0x7fffu + ((v.u >> 16) & 1u);   // RNE
    return (unsigned short)(r >> 16);
}
__device__ __forceinline__ float bf2f(unsigned short b) {
    union { unsigned u; float f; } v; v.u = ((unsigned)b) << 16;
    return v.f;
}

// ---- fused prep: x->bf16 convert  +  weight transpose/convert  + qkv bias --
__global__ void prep_kernel(const float* __restrict__ x,
                            const float* __restrict__ Wq, const float* __restrict__ Wk,
                            const float* __restrict__ Wv, const float* __restrict__ Wo,
                            const float* __restrict__ bq, const float* __restrict__ bk,
                            const float* __restrict__ bv,
                            unsigned short* __restrict__ xb,      // [MR*CC] bf16
                            unsigned short* __restrict__ WqkvT,   // [1792][768]
                            unsigned short* __restrict__ WoT,     // [768][640] (K-padded)
                            float* __restrict__ bqkv)             // [1792]
{
    const int N4  = MR * CC / 4;        // 7077888 float4 groups of x
    const int NW1 = NQKV * CC;          // 1792*768
    const int NW2 = CC * KPAD;          // 768*640
    int idx = blockIdx.x * 256 + threadIdx.x;
    if (idx < N4) {
        float4 a = ((const float4*)x)[idx];
        uint2 o;
        o.x = (unsigned)f2bf(a.x) | ((unsigned)f2bf(a.y) << 16);
        o.y = (unsigned)f2bf(a.z) | ((unsigned)f2bf(a.w) << 16);
        ((uint2*)xb)[idx] = o;
        return;
    }
    idx -= N4;
    if (idx < NW1) {
        int n = idx / CC, k = idx % CC;
        float v = 0.f;
        if      (n < 576)  v = Wq[k * HID + n];
        else if (n < 1152) v = Wk[k * HID + (n - 576)];
        else if (n < 1728) v = Wv[k * HID + (n - 1152)];
        WqkvT[idx] = f2bf(v);
    } else if (idx < NW1 + NW2) {
        int i = idx - NW1;
        int c = i / KPAD, h = i % KPAD;
        WoT[i] = (h < HID) ? f2bf(Wo[h * CC + c]) : (unsigned short)0;
    } else if (idx < NW1 + NW2 + NQKV) {
        int n = idx - NW1 - NW2;
        float v = 0.f;
        if      (n < 576)  v = bq[n];
        else if (n < 1152) v = bk[n - 576];
        else if (n < 1728) v = bv[n - 1152];
        bqkv[n] = v;
    }
}

// ============================================================================
// 256x256 8-phase GEMM, one barrier per phase (round-4 proven schedule).
// Staging: 1 half-tile per phase,
//   buf1 tile 2t+1: Ah0 @ p8(prev), Ah1 @ p1, Bh0 @ p2, Bh1 @ p3
//   buf0 tile 2t+2: Ah0 @ p4, Ah1 @ p5, Bh0 @ p6, Bh1 @ p7
// Swap waits: vmcnt(2) after MFMA at p4 (buf1 ready) and p8 (buf0 ready).
// ============================================================================

#define BARR() asm volatile("s_barrier" ::: "memory")
#define MFMA_BEGIN() do { asm volatile("s_waitcnt lgkmcnt(0)" ::: "memory"); \
                          __builtin_amdgcn_sched_barrier(0); \
                          __builtin_amdgcn_s_setprio(1); } while (0)
#define MFMA_END() do { __builtin_amdgcn_s_setprio(0); \
                        __builtin_amdgcn_sched_barrier(0); } while (0)
#define VMCNT2() asm volatile("s_waitcnt vmcnt(2)" ::: "memory")
#define VMCNT0() asm volatile("s_waitcnt vmcnt(0)" ::: "memory")

// stage one 128x64 half-tile (2 x global_load_lds x 512 threads = 16 KB)
#define STG(BI, MAT, H, KT, G) do { \
    const unsigned short* _s0 = (G) + (size_t)(H) * 128 * ldk + (size_t)(KT) * 64 + off0; \
    const unsigned short* _s1 = (G) + (size_t)(H) * 128 * ldk + (size_t)(KT) * 64 + off1; \
    __builtin_amdgcn_global_load_lds((const __attribute__((address_space(1))) void*)_s0, \
        (__attribute__((address_space(3))) void*)&lds[BI][MAT][(H) * 8192 + wave * 512], 16, 0, 0); \
    __builtin_amdgcn_global_load_lds((const __attribute__((address_space(1))) void*)_s1, \
        (__attribute__((address_space(3))) void*)&lds[BI][MAT][(H) * 8192 + 4096 + wave * 512], 16, 0, 0); \
} while (0)

__device__ __forceinline__ void read_a4(const char* L, int base, int fr, int kg, vbf16x8 o[4][2]) {
#pragma unroll
    for (int m = 0; m < 4; ++m)
#pragma unroll
        for (int ks = 0; ks < 2; ++ks) {
            int R = base + m * 16 + fr;
            o[m][ks] = *(const vbf16x8*)(L + (size_t)R * 128 + ((((ks * 4 + kg) ^ (R & 7))) << 4));
        }
}
__device__ __forceinline__ void read_b2(const char* L, int base, int fr, int kg, vbf16x8 o[2][2]) {
#pragma unroll
    for (int n = 0; n < 2; ++n)
#pragma unroll
        for (int ks = 0; ks < 2; ++ks) {
            int R = base + n * 16 + fr;
            o[n][ks] = *(const vbf16x8*)(L + (size_t)R * 128 + ((((ks * 4 + kg) ^ (R & 7))) << 4));
        }
}
__device__ __forceinline__ void mfma16(vf32x4 acc[8][4], const vbf16x8 a[4][2],
                                       const vbf16x8 b[2][2], int mo, int no) {
#pragma unroll
    for (int m = 0; m < 4; ++m)
#pragma unroll
        for (int n = 0; n < 2; ++n)
#pragma unroll
            for (int ks = 0; ks < 2; ++ks)
                acc[mo + m][no + n] = __builtin_amdgcn_mfma_f32_16x16x32_bf16(
                    a[m][ks], b[n][ks], acc[mo + m][no + n], 0, 0, 0);
}

template <int EPI>   // 0: bf16 out, 1: f32 out
__global__ __launch_bounds__(512, 2) void gemm8p(const unsigned short* __restrict__ A,
                                                 const unsigned short* __restrict__ Bt,
                                                 void* __restrict__ Cv,
                                                 const float* __restrict__ bias,
                                                 int N, int ldk, int NITER, int nbn)
{
    __shared__ unsigned short lds[2][2][16384];   // [buf][A/B][256*64] = 128 KiB
    int tid = threadIdx.x;
    int lane = tid & 63, wave = tid >> 6;
    int fr = lane & 15, kg = lane >> 4;
    int wm = wave >> 2, wn = wave & 3;

    // XCD-aware swizzle (grid % 8 == 0)
    int cpx = gridDim.x >> 3;
    int wg = (blockIdx.x & 7) * cpx + (blockIdx.x >> 3);
    int bm = wg / nbn, bn = wg % nbn;

    const unsigned short* Ag = A + (size_t)bm * 256 * ldk;
    const unsigned short* Bg = Bt + (size_t)bn * 256 * ldk;

    // per-thread staging offsets (source pre-swizzled: cb ^= row&7)
    int c0 = tid, c1 = 512 + tid;
    int r0 = c0 >> 3, q0 = c0 & 7, r1 = c1 >> 3, q1 = c1 & 7;
    size_t off0 = (size_t)r0 * ldk + (size_t)((q0 ^ (r0 & 7)) << 3);
    size_t off1 = (size_t)r1 * ldk + (size_t)((q1 ^ (r1 & 7)) << 3);

    vf32x4 acc[8][4] = {};
    vbf16x8 a0[4][2], a1[4][2], b0[2][2], b1[2][2];

    // prologue: tile0 -> buf0 (4 halves), tile1 A-h0 -> buf1
    STG(0, 0, 0, 0, Ag); STG(0, 0, 1, 0, Ag);
    STG(0, 1, 0, 0, Bg); STG(0, 1, 1, 0, Bg);
    STG(1, 0, 0, 1, Ag);
    VMCNT2();
    BARR();

    for (int t = 0; t < NITER; ++t) {
        bool last = (t == NITER - 1);
        int k1 = 2 * t + 1, k2 = 2 * t + 2, k3 = 2 * t + 3;
        {   // ---------------- buf0 : tile 2t ----------------
            const char* LA = (const char*)lds[0][0];
            const char* LB = (const char*)lds[0][1];
            // p1
            read_a4(LA, wm * 128, fr, kg, a0);
            read_b2(LB, wn * 64, fr, kg, b0);
            STG(1, 0, 1, k1, Ag);
            MFMA_BEGIN(); mfma16(acc, a0, b0, 0, 0); MFMA_END(); BARR();
            // p2
            read_b2(LB, wn * 64 + 32, fr, kg, b1);
            STG(1, 1, 0, k1, Bg);
            MFMA_BEGIN(); mfma16(acc, a0, b1, 0, 2); MFMA_END(); BARR();
            // p3  (last reads of buf0)
            read_a4(LA, wm * 128 + 64, fr, kg, a1);
            STG(1, 1, 1, k1, Bg);
            MFMA_BEGIN(); mfma16(acc, a1, b1, 4, 2); MFMA_END(); BARR();
            // p4  (stage into buf0 ok: reads done at p3 barrier; swap-wait for buf1)
            if (!last) STG(0, 0, 0, k2, Ag);
            MFMA_BEGIN(); mfma16(acc, a1, b0, 4, 0); MFMA_END();
            if (!last) VMCNT2(); else VMCNT0();
            BARR();
        }
        {   // ---------------- buf1 : tile 2t+1 ----------------
            const char* LA = (const char*)lds[1][0];
            const char* LB = (const char*)lds[1][1];
            // p5
            read_a4(LA, wm * 128, fr, kg, a0);
            read_b2(LB, wn * 64, fr, kg, b0);
            if (!last) STG(0, 0, 1, k2, Ag);
            MFMA_BEGIN(); mfma16(acc, a0, b0, 0, 0); MFMA_END(); BARR();
            // p6
            read_b2(LB, wn * 64 + 32, fr, kg, b1);
            if (!last) STG(0, 1, 0, k2, Bg);
            MFMA_BEGIN(); mfma16(acc, a0, b1, 0, 2); MFMA_END(); BARR();
            // p7  (last reads of buf1)
            read_a4(LA, wm * 128 + 64, fr, kg, a1);
            if (!last) STG(0, 1, 1, k2, Bg);
            MFMA_BEGIN(); mfma16(acc, a1, b1, 4, 2); MFMA_END(); BARR();
            // p8  (stage into buf1 ok: reads done at p7 barrier; swap-wait for buf0)
            if (!last) STG(1, 0, 0, k3, Ag);
            MFMA_BEGIN(); mfma16(acc, a1, b0, 4, 0); MFMA_END();
            if (!last) VMCNT2(); else VMCNT0();
            BARR();
        }
    }

    // epilogue: C/D layout col = lane&15, row = (lane>>4)*4 + reg
    int row0 = bm * 256 + wm * 128 + kg * 4;
    int col0 = bn * 256 + wn * 64;
#pragma unroll
    for (int m = 0; m < 8; ++m) {
#pragma unroll
        for (int n = 0; n < 4; ++n) {
            int c = col0 + n * 16 + fr;
            float bb = bias[c];
            int r = row0 + m * 16;
#pragma unroll
            for (int j = 0; j < 4; ++j) {
                float v = acc[m][n][j] + bb;
                if (EPI == 0) ((unsigned short*)Cv)[(size_t)(r + j) * N + c] = f2bf(v);
                else          ((float*)Cv)[(size_t)(r + j) * N + c] = v;
            }
        }
    }
}

// ---- max over batch: maxk[t][h] = max_b k[b,t,h] ----------------------------
__global__ void maxk_kernel(const unsigned short* __restrict__ qkv, float* __restrict__ maxk)
{
    int idx = blockIdx.x * 256 + threadIdx.x;      // t*576 + h
    if (idx >= TT * HID) return;
    int t = idx / HID, h = idx % HID;
    const unsigned short* p = qkv + (size_t)t * NQKV + 576 + h;
    const size_t stride = (size_t)TT * NQKV;
    float m0 = -1e30f, m1 = -1e30f, m2 = -1e30f, m3 = -1e30f;
#pragma unroll 4
    for (int b = 0; b < BB; b += 4) {
        m0 = fmaxf(m0, bf2f(p[(size_t)(b + 0) * stride]));
        m1 = fmaxf(m1, bf2f(p[(size_t)(b + 1) * stride]));
        m2 = fmaxf(m2, bf2f(p[(size_t)(b + 2) * stride]));
        m3 = fmaxf(m3, bf2f(p[(size_t)(b + 3) * stride]));
    }
    maxk[idx] = fmaxf(fmaxf(m0, m1), fmaxf(m2, m3));
}

// ---- num/den partial sums over t (split into 4 chunks, no atomics) ---------
__global__ void numden_kernel(const unsigned short* __restrict__ qkv,
                              const float* __restrict__ maxk,
                              float* __restrict__ num_p, float* __restrict__ den_p)
{
    int b = blockIdx.x, tc = blockIdx.y, h = threadIdx.x;   // 576 threads
    float num = 0.f, den = 0.f;
    int t0 = tc * 144;
    for (int t = t0; t < t0 + 144; ++t) {
        const unsigned short* row = qkv + (size_t)(b * TT + t) * NQKV;
        float kk = bf2f(row[576 + h]);
        float vv = bf2f(row[1152 + h]);
        float e  = __expf(kk - maxk[t * HID + h]);
        den += e;
        num += e * vv;
    }
    int o = (tc * BB + b) * HID + h;
    num_p[o] = num;
    den_p[o] = den;
}

// ---- y = sigmoid(q) * num/den  (bf16, row stride KPAD=640) -----------------
// Pad columns 576..639 are never written: GEMM2's WoT rows k>=576 are exact
// zeros, so those A-operands contribute value*0 = 0 for any finite data, and
// the region (inside xb) is rewritten with finite bf16 by prep each call.
__global__ void y_kernel(const unsigned short* __restrict__ qkv,
                         const float* __restrict__ num_p, const float* __restrict__ den_p,
                         unsigned short* __restrict__ y)
{
    int idx = blockIdx.x * 256 + threadIdx.x;
    if (idx >= MR * (HID / 8)) return;
    int h8 = idx % (HID / 8), row = idx / (HID / 8);
    int b = row / TT;
    uint4 q4 = *(const uint4*)(qkv + (size_t)row * NQKV + h8 * 8);
    float num[8], den[8];
#pragma unroll
    for (int j = 0; j < 8; ++j) { num[j] = 0.f; den[j] = 0.f; }
#pragma unroll
    for (int tc = 0; tc < 4; ++tc) {
        const float* np = num_p + (size_t)(tc * BB + b) * HID + h8 * 8;
        const float* dp = den_p + (size_t)(tc * BB + b) * HID + h8 * 8;
#pragma unroll
        for (int j = 0; j < 8; ++j) { num[j] += np[j]; den[j] += dp[j]; }
    }
    unsigned qs[4] = { q4.x, q4.y, q4.z, q4.w };
    unsigned o[4];
#pragma unroll
    for (int w2 = 0; w2 < 4; ++w2) {
        float qa = bf2f((unsigned short)(qs[w2] & 0xffff));
        float qb = bf2f((unsigned short)(qs[w2] >> 16));
        float r0 = num[w2 * 2]     / den[w2 * 2];
        float r1 = num[w2 * 2 + 1] / den[w2 * 2 + 1];
        float y0 = (1.f / (1.f + __expf(-qa))) * r0;
        float y1 = (1.f / (1.f + __expf(-qb))) * r1;
        o[w2] = (unsigned)f2bf(y0) | ((unsigned)f2bf(y1) << 16);
    }
    uint4 ov; ov.x = o[0]; ov.y = o[1]; ov.z = o[2]; ov.w = o[3];
    *(uint4*)(y + (size_t)row * KPAD + h8 * 8) = ov;
}

// ---------------------------------------------------------------------------
extern "C" void kernel_launch(void* const* d_in, const int* in_sizes, int n_in,
                              void* d_out, int out_size, void* d_ws, size_t ws_size,
                              hipStream_t stream)
{
    const float* x  = (const float*)d_in[0];
    const float* Wq = (const float*)d_in[1];
    const float* bq = (const float*)d_in[2];
    const float* Wk = (const float*)d_in[3];
    const float* bk = (const float*)d_in[4];
    const float* Wv = (const float*)d_in[5];
    const float* bv = (const float*)d_in[6];
    const float* Wo = (const float*)d_in[7];
    const float* bo = (const float*)d_in[8];
    float* out = (float*)d_out;

    char* ws = (char*)d_ws;
    size_t off = 0;
    auto alloc = [&](size_t bytes) -> void* {
        off = (off + 255) & ~(size_t)255;
        void* p = ws + off;
        off += bytes;
        return p;
    };

    unsigned short* xb    = (unsigned short*)alloc((size_t)MR * CC * 2);     // 56.6 MB (reused for y[MR][640])
    unsigned short* WqkvT = (unsigned short*)alloc((size_t)NQKV * CC * 2);   // 2.75 MB
    unsigned short* WoT   = (unsigned short*)alloc((size_t)CC * KPAD * 2);   // 0.98 MB
    float*          bqkv  = (float*)alloc((size_t)NQKV * 4);
    unsigned short* qkv   = (unsigned short*)alloc((size_t)MR * NQKV * 2);   // 132 MB
    float*          maxk  = (float*)alloc((size_t)TT * HID * 4);             // 1.3 MB
    float*          num_p = (float*)alloc((size_t)4 * BB * HID * 4);
    float*          den_p = (float*)alloc((size_t)4 * BB * HID * 4);
    unsigned short* yb    = xb;   // alias: x_bf16 dead after gemm_qkv

    // 1) fused prep: x->bf16 + weight transpose/convert + bias pack
    {
        int total = MR * CC / 4 + NQKV * CC + CC * KPAD + NQKV;   // 8947456
        prep_kernel<<<dim3((total + 255) / 256), dim3(256), 0, stream>>>(
            x, Wq, Wk, Wv, Wo, bq, bk, bv, xb, WqkvT, WoT, bqkv);
    }
    // 2) fused QKV GEMM: [36864,768] x [768,1792] -> bf16 qkv   (grid 144*7=1008)
    gemm8p<0><<<dim3((MR / 256) * (NQKV / 256)), dim3(512), 0, stream>>>(
        xb, WqkvT, (void*)qkv, bqkv, NQKV, CC, CC / 128, NQKV / 256);
    // 3) max over batch
    maxk_kernel<<<dim3(TT * HID / 256), dim3(256), 0, stream>>>(qkv, maxk);
    // 4) num/den partials
    numden_kernel<<<dim3(BB, 4), dim3(HID), 0, stream>>>(qkv, maxk, num_p, den_p);
    // 5) y = sigmoid(q) * num/den (row stride 640; pad cols never written)
    {
        int total = MR * (HID / 8);   // 2654208 = 10368 * 256
        y_kernel<<<dim3(total / 256), dim3(256), 0, stream>>>(qkv, num_p, den_p, yb);
    }
    // 6) output GEMM: [36864,640] x [640,768] + bo -> f32 out   (grid 144*3=432)
    gemm8p<1><<<dim3((MR / 256) * (CC / 256)), dim3(512), 0, stream>>>(
        yb, WoT, (void*)out, bo, CC, KPAD, KPAD / 128, CC / 256);
}